// Round 4
// baseline (4116.720 us; speedup 1.0000x reference)
//
#include <hip/hip_runtime.h>
#include <math.h>

// decoderRNN: attention LSTM caption decoder, teacher-forced.
// B=64 L=49 F=2048 T=32 V=15000 E=H=A=512
#define B_ 64
#define L_ 49
#define F_DIM 2048
#define T_ 32
#define V_ 15000
#define E_ 512
#define H_ 512
#define A_ 512

typedef __attribute__((ext_vector_type(8))) short short8;
typedef __attribute__((ext_vector_type(4))) float f32x4;

__device__ __forceinline__ unsigned short f2b(float x) {
    union { float f; unsigned int u; } v; v.f = x;
    unsigned int r = v.u + 0x7FFF + ((v.u >> 16) & 1);
    return (unsigned short)(r >> 16);
}

// ---------------- f32 -> bf16 cast, row-strided ----------------
__global__ __launch_bounds__(256)
void k_cast(const float* __restrict__ src, unsigned short* __restrict__ dst,
            int cols, int src_stride)
{
    const int r  = blockIdx.y;
    const int c4 = blockIdx.x * 256 + threadIdx.x;
    if (c4 * 4 >= cols) return;
    float4 v = *reinterpret_cast<const float4*>(src + (size_t)r * src_stride + c4 * 4);
    ushort4 o;
    o.x = f2b(v.x); o.y = f2b(v.y); o.z = f2b(v.z); o.w = f2b(v.w);
    *reinterpret_cast<ushort4*>(dst + (size_t)r * cols + c4 * 4) = o;
}

// ---- bf16 MFMA GEMM: C[M,N] = A[M,K] @ W^T (+bias0 for n<N0) ----
// W rows [0,N0) from W0 (stride ldw0), [N0,N) from W1 (stride ldw1).
// 128x128 tile, BK=32, 4 waves; permT!=0: row = (m&63)*permT + (m>>6)
#define LDSW 40
__global__ __launch_bounds__(256)
void gemm_mfma(const unsigned short* __restrict__ A, int lda,
               const unsigned short* __restrict__ W0, int ldw0, int N0,
               const unsigned short* __restrict__ W1, int ldw1,
               const float* __restrict__ bias0,
               float* __restrict__ C, int ldc,
               int M, int N, int K, int permT)
{
    __shared__ unsigned short As[128 * LDSW];
    __shared__ unsigned short Ws[128 * LDSW];

    const int tid  = threadIdx.x;
    const int m0   = blockIdx.x * 128;
    const int n0   = blockIdx.y * 128;
    const int wave = tid >> 6;
    const int lane = tid & 63;
    const int wr   = (wave >> 1) * 64;
    const int wc   = (wave & 1) * 64;

    f32x4 acc[4][4];
    #pragma unroll
    for (int i = 0; i < 4; ++i)
        #pragma unroll
        for (int j = 0; j < 4; ++j)
            acc[i][j] = (f32x4)(0.f);

    const int fr = lane & 15;
    const int fk = (lane >> 4) * 8;

    for (int kc = 0; kc < K; kc += 32) {
        float4 av[2], wv[2];
        #pragma unroll
        for (int i = 0; i < 2; ++i) {
            const int idx = tid + i * 256;
            const int row = idx >> 2;
            const int seg = idx & 3;
            av[i] = make_float4(0.f, 0.f, 0.f, 0.f);
            wv[i] = make_float4(0.f, 0.f, 0.f, 0.f);
            if (m0 + row < M)
                av[i] = *reinterpret_cast<const float4*>(A + (size_t)(m0 + row) * lda + kc + seg * 8);
            const int n_abs = n0 + row;
            if (n_abs < N) {
                const unsigned short* wrow = (n_abs < N0)
                    ? (W0 + (size_t)n_abs * ldw0)
                    : (W1 + (size_t)(n_abs - N0) * ldw1);
                wv[i] = *reinterpret_cast<const float4*>(wrow + kc + seg * 8);
            }
        }
        __syncthreads();
        #pragma unroll
        for (int i = 0; i < 2; ++i) {
            const int idx = tid + i * 256;
            const int row = idx >> 2;
            const int seg = idx & 3;
            *reinterpret_cast<float4*>(&As[row * LDSW + seg * 8]) = av[i];
            *reinterpret_cast<float4*>(&Ws[row * LDSW + seg * 8]) = wv[i];
        }
        __syncthreads();

        short8 afr[4], bfr[4];
        #pragma unroll
        for (int mf = 0; mf < 4; ++mf)
            afr[mf] = *reinterpret_cast<const short8*>(&As[(wr + mf * 16 + fr) * LDSW + fk]);
        #pragma unroll
        for (int nf = 0; nf < 4; ++nf)
            bfr[nf] = *reinterpret_cast<const short8*>(&Ws[(wc + nf * 16 + fr) * LDSW + fk]);

        #pragma unroll
        for (int mf = 0; mf < 4; ++mf)
            #pragma unroll
            for (int nf = 0; nf < 4; ++nf)
                acc[mf][nf] = __builtin_amdgcn_mfma_f32_16x16x32_bf16(
                    afr[mf], bfr[nf], acc[mf][nf], 0, 0, 0);
    }

    const int cr = (lane >> 4) * 4;
    const int cc = lane & 15;
    #pragma unroll
    for (int nf = 0; nf < 4; ++nf) {
        const int n = n0 + wc + nf * 16 + cc;
        if (n >= N) continue;
        const float bv = (bias0 && n < N0) ? bias0[n] : 0.f;
        #pragma unroll
        for (int mf = 0; mf < 4; ++mf) {
            #pragma unroll
            for (int r = 0; r < 4; ++r) {
                const int m = m0 + wr + mf * 16 + cr + r;
                if (m >= M) continue;
                const size_t row = permT ? ((size_t)(m & 63) * permT + (size_t)(m >> 6))
                                         : (size_t)m;
                C[row * (size_t)ldc + n] = acc[mf][nf][r] + bv;
            }
        }
    }
}

// ---------------- generic tiled f32 GEMM (small/prologue matmuls) ----------------
__global__ __launch_bounds__(256)
void gemm64(const float* __restrict__ A, int lda,
            const float* __restrict__ W0, int ldw0, int N0,
            const float* __restrict__ W1, int ldw1,
            const float* __restrict__ bias0, const float* __restrict__ bias1,
            const float* __restrict__ biasX,
            float* __restrict__ C, int ldc,
            int N, int K, int permT, int obf)
{
    __shared__ float As[16][64];
    __shared__ float Ws[16][64];

    const int tid = threadIdx.x;
    const int m0  = blockIdx.x * 64;
    const int n0  = blockIdx.y * 64;

    const int lr = tid >> 2;
    const int kq = tid & 3;

    const int n_abs = n0 + lr;
    const bool wvalid = (n_abs < N);
    const float* wrow = nullptr;
    if (wvalid)
        wrow = (n_abs < N0) ? (W0 + (size_t)n_abs * ldw0)
                            : (W1 + (size_t)(n_abs - N0) * ldw1);
    const float* arow = A + (size_t)(m0 + lr) * lda;

    const int ty = tid >> 4;
    const int tx = tid & 15;

    float acc[4][4] = {{0.f}};

    for (int kc = 0; kc < K; kc += 16) {
        float4 av = *reinterpret_cast<const float4*>(arow + kc + kq * 4);
        float4 wv = make_float4(0.f, 0.f, 0.f, 0.f);
        if (wvalid)
            wv = *reinterpret_cast<const float4*>(wrow + kc + kq * 4);

        __syncthreads();
        As[kq * 4 + 0][lr] = av.x;
        As[kq * 4 + 1][lr] = av.y;
        As[kq * 4 + 2][lr] = av.z;
        As[kq * 4 + 3][lr] = av.w;
        Ws[kq * 4 + 0][lr] = wv.x;
        Ws[kq * 4 + 1][lr] = wv.y;
        Ws[kq * 4 + 2][lr] = wv.z;
        Ws[kq * 4 + 3][lr] = wv.w;
        __syncthreads();

        #pragma unroll
        for (int kk = 0; kk < 16; ++kk) {
            const float4 a4 = *reinterpret_cast<const float4*>(&As[kk][ty * 4]);
            const float4 w4 = *reinterpret_cast<const float4*>(&Ws[kk][tx * 4]);
            const float aa[4] = {a4.x, a4.y, a4.z, a4.w};
            const float ww[4] = {w4.x, w4.y, w4.z, w4.w};
            #pragma unroll
            for (int i = 0; i < 4; ++i)
                #pragma unroll
                for (int j = 0; j < 4; ++j)
                    acc[i][j] = fmaf(aa[i], ww[j], acc[i][j]);
        }
    }

    #pragma unroll
    for (int i = 0; i < 4; ++i) {
        const int m = m0 + ty * 4 + i;
        #pragma unroll
        for (int j = 0; j < 4; ++j) {
            const int n = n0 + tx * 4 + j;
            if (n >= N) continue;
            float v = acc[i][j];
            if (bias0 && n < N0) v += bias0[n];
            if (bias1 && n >= N0) v += bias1[n - N0];
            if (biasX) v += biasX[n];
            const size_t row = permT ? ((size_t)(m & 63) * permT + (size_t)(m >> 6))
                                     : (size_t)m;
            if (obf) ((unsigned short*)C)[row * (size_t)ldc + n] = f2b(v);
            else     C[row * (size_t)ldc + n] = v;
        }
    }
}

// ---------------- mean over L ----------------
__global__ __launch_bounds__(256)
void k_mean(const float* __restrict__ feat, float* __restrict__ mean_f)
{
    const int idx = blockIdx.x * 256 + threadIdx.x;
    const int b = idx >> 11;
    const int f = idx & 2047;
    const float* p = feat + (size_t)b * L_ * F_DIM + f;
    float s = 0.f;
    #pragma unroll 7
    for (int l = 0; l < L_; ++l) s += p[(size_t)l * F_DIM];
    mean_f[idx] = s * (1.0f / 49.0f);
}

// ---------------- embedding gather ----------------
__global__ __launch_bounds__(256)
void k_embgather(const float* __restrict__ table, const int* __restrict__ caps,
                 float* __restrict__ emb_seq)
{
    const int idx = blockIdx.x * 256 + threadIdx.x;
    const int e   = idx & 511;
    const int row = idx >> 9;
    const int t   = row >> 6;
    const int b   = row & 63;
    const int tok = caps[b * T_ + t];
    emb_seq[idx] = table[(size_t)tok * E_ + e];
}

// ---------------- persistent recurrence kernel ----------------
// grid 160 x 256, 1 block/CU (96KB LDS) -> all blocks co-resident.
// Phase A: block g owns 16 rows of Wc=[U_a;W_hh] (bf16 in LDS), computes
// att2g[:, g*16..+16] via MFMA from global bf16 h. Phase B: blocks 0..127 =
// (b, half): scores -> softmax -> gates -> pointwise, update h/c.
// Grid barrier: MONOTONE device-scope counter (no reset -> no race);
// __threadfence provides cross-XCD L2 wb/inv.
#define NBLK_RECUR 160u

__device__ __forceinline__ void gridbar(unsigned* cnt, unsigned target)
{
    __threadfence();                 // release: push my writes past L2
    __syncthreads();
    if (threadIdx.x == 0) {
        atomicAdd(cnt, 1u);
        while (atomicAdd(cnt, 0u) < target) __builtin_amdgcn_s_sleep(2);
    }
    __syncthreads();
    __threadfence();                 // acquire: drop stale cached lines
}

__global__ __launch_bounds__(256)
void k_recur(unsigned short* __restrict__ hbf,      // [64][512] bf16 (in/out)
             float* __restrict__ att2g,             // [64][2560]
             const float* __restrict__ U_a,         // [512][512]
             const float* __restrict__ W_hh,        // [2048][512]
             const float* __restrict__ U_a_b,       // [512]
             const float* __restrict__ attF,        // [3136][2560] (att1 | featW)
             const float* __restrict__ g_emb,       // [32][64][2048]
             const float* __restrict__ v_w, const float* __restrict__ v_b,
             float* __restrict__ c_st,              // [64][512] f32 (in/out)
             unsigned short* __restrict__ h_hist,   // [32][64][512] bf16
             unsigned* __restrict__ bar)
{
    __shared__ unsigned short Wc[16 * 520];
    __shared__ unsigned short hsd[64 * 520];
    __shared__ float a2[512];
    __shared__ float ghh[1024];
    __shared__ float wl[64];
    __shared__ float gates[1024];
    __shared__ float vws[512];

    const int g    = blockIdx.x;
    const int tid  = threadIdx.x;
    const int R    = g * 16;
    const int wave = tid >> 6;
    const int lane = tid & 63;

    // ---- one-time: load weight slice (f32 -> bf16 LDS), v_w ----
    for (int idx = tid; idx < 2048; idx += 256) {      // 16 rows x 128 float4
        const int r  = idx >> 7;
        const int kq = idx & 127;
        const int n  = R + r;
        const float* src = (n < 512) ? (U_a + (size_t)n * 512)
                                     : (W_hh + (size_t)(n - 512) * 512);
        float4 v = *reinterpret_cast<const float4*>(src + kq * 4);
        unsigned short* d = &Wc[r * 520 + kq * 4];
        d[0] = f2b(v.x); d[1] = f2b(v.y); d[2] = f2b(v.z); d[3] = f2b(v.w);
    }
    for (int i = tid; i < 512; i += 256) vws[i] = v_w[i];

    const int isB  = (g < 128);
    const int b    = g >> 1;
    const int half = g & 1;
    __syncthreads();

    for (int t = 0; t < T_; ++t) {
        // ================= phase A =================
        for (int idx = tid; idx < 4096; idx += 256) {  // 64 rows x 64 short8
            const int bb = idx >> 6;
            const int s8 = idx & 63;
            *reinterpret_cast<short8*>(&hsd[bb * 520 + s8 * 8]) =
                *reinterpret_cast<const short8*>(hbf + bb * 512 + s8 * 8);
        }
        __syncthreads();

        f32x4 acc = (f32x4)(0.f);
        const int frow = lane & 15;
        const int fko  = (lane >> 4) * 8;
        #pragma unroll
        for (int ks = 0; ks < 16; ++ks) {
            short8 af = *reinterpret_cast<const short8*>(&hsd[(wave * 16 + frow) * 520 + ks * 32 + fko]);
            short8 bf = *reinterpret_cast<const short8*>(&Wc[frow * 520 + ks * 32 + fko]);
            acc = __builtin_amdgcn_mfma_f32_16x16x32_bf16(af, bf, acc, 0, 0, 0);
        }
        #pragma unroll
        for (int r = 0; r < 4; ++r) {
            const int babs = wave * 16 + (lane >> 4) * 4 + r;
            att2g[(size_t)babs * 2560 + R + (lane & 15)] = acc[r];
        }
        gridbar(bar, (unsigned)(2 * t + 1) * NBLK_RECUR);

        // ================= phase B =================
        if (isB) {
            for (int i = tid; i < 512; i += 256)
                a2[i] = att2g[(size_t)b * 2560 + i] + U_a_b[i];
            for (int i = tid; i < 1024; i += 256) {
                const int grp = i >> 8, j = i & 255;
                ghh[i] = att2g[(size_t)b * 2560 + 512 + grp * 512 + half * 256 + j];
            }
            __syncthreads();

            for (int l = wave; l < L_; l += 4) {
                const float* a1 = attF + (size_t)(b * L_ + l) * 2560;
                float s = 0.f;
                for (int a = lane; a < 512; a += 64)
                    s += tanhf(a1[a] + a2[a]) * vws[a];
                #pragma unroll
                for (int off = 32; off > 0; off >>= 1) s += __shfl_down(s, off);
                if (lane == 0) wl[l] = s + v_b[0];
            }
            __syncthreads();

            if (tid < 64) {
                float v = (lane < L_) ? wl[lane] : -3.0e38f;
                float mx = v;
                #pragma unroll
                for (int off = 32; off > 0; off >>= 1) mx = fmaxf(mx, __shfl_xor(mx, off));
                float e = (lane < L_) ? __expf(v - mx) : 0.f;
                float sum = e;
                #pragma unroll
                for (int off = 32; off > 0; off >>= 1) sum += __shfl_xor(sum, off);
                if (lane < L_) wl[lane] = e / sum;
            }
            __syncthreads();

            {
                const int grp = tid >> 6;
                const int j4  = (tid & 63) * 4;
                const int cg_ = grp * 512 + half * 256 + j4;
                const float* fW = attF + (size_t)(b * L_) * 2560 + 512 + cg_;
                float4 g4 = *reinterpret_cast<const float4*>(
                    g_emb + ((size_t)t * 64 + b) * 2048 + cg_);
                const float4 gh4 = *reinterpret_cast<const float4*>(&ghh[grp * 256 + j4]);
                g4.x += gh4.x; g4.y += gh4.y; g4.z += gh4.z; g4.w += gh4.w;
                #pragma unroll 7
                for (int l = 0; l < L_; ++l) {
                    const float w = wl[l];
                    const float4 f4 = *reinterpret_cast<const float4*>(fW + (size_t)l * 2560);
                    g4.x = fmaf(w, f4.x, g4.x);
                    g4.y = fmaf(w, f4.y, g4.y);
                    g4.z = fmaf(w, f4.z, g4.z);
                    g4.w = fmaf(w, f4.w, g4.w);
                }
                *reinterpret_cast<float4*>(&gates[grp * 256 + j4]) = g4;
            }
            __syncthreads();

            {
                const int n = half * 256 + tid;
                const float gi = gates[tid], gf = gates[256 + tid];
                const float gg = gates[512 + tid], go = gates[768 + tid];
                const float i = 1.f / (1.f + __expf(-gi));
                const float f = 1.f / (1.f + __expf(-gf));
                const float gv = tanhf(gg);
                const float o = 1.f / (1.f + __expf(-go));
                const float c = f * c_st[b * 512 + n] + i * gv;
                const float h = o * tanhf(c);
                c_st[b * 512 + n] = c;
                const unsigned short hb = f2b(h);
                hbf[b * 512 + n] = hb;
                h_hist[((size_t)t * 64 + b) * 512 + n] = hb;
            }
        }
        gridbar(bar, (unsigned)(2 * t + 2) * NBLK_RECUR);
    }
}

extern "C" void kernel_launch(void* const* d_in, const int* in_sizes, int n_in,
                              void* d_out, int out_size, void* d_ws, size_t ws_size,
                              hipStream_t stream)
{
    const float* features = (const float*)d_in[0];
    const int*   captions = (const int*)d_in[1];
    const float* init_h_W = (const float*)d_in[3];
    const float* init_h_b = (const float*)d_in[4];
    const float* init_c_W = (const float*)d_in[5];
    const float* init_c_b = (const float*)d_in[6];
    const float* W_a_W    = (const float*)d_in[7];
    const float* W_a_b    = (const float*)d_in[8];
    const float* U_a_W    = (const float*)d_in[9];
    const float* U_a_b    = (const float*)d_in[10];
    const float* v_a_W    = (const float*)d_in[11];
    const float* v_a_b    = (const float*)d_in[12];
    const float* embed    = (const float*)d_in[13];
    const float* W_ih     = (const float*)d_in[14];
    const float* W_hh     = (const float*)d_in[15];
    const float* b_ih     = (const float*)d_in[16];
    const float* b_hh     = (const float*)d_in[17];
    const float* fc_W     = (const float*)d_in[18];
    const float* fc_b     = (const float*)d_in[19];
    float* out = (float*)d_out;

    // ---- workspace (floats), all disjoint ----
    float* ws      = (float*)d_ws;
    float* mean_f  = ws;                                        // [0, 131072)
    float* c_st    = ws + 131072;                               // [131072, 163840)
    unsigned short* h_bf   = (unsigned short*)(ws + 163840);    // 16384 fl
    unsigned short* h_hist = (unsigned short*)(ws + 180224);    // 524288 fl
    float* att2g   = ws + 704512;                               // 163840 fl
    unsigned short* fcW_bf = (unsigned short*)(ws + 868352);    // 3840000 fl
    unsigned* bar  = (unsigned*)(ws + 4708352);                 // 32 fl
    // ws high-water: 4,708,384 floats = 18.8 MB

    // ---- big transients in d_out (out_size = 30,720,000 fl), all disjoint,
    // all dead before the logits GEMM overwrites out ----
    float* g_emb = out;                                          // [0, 4194304)
    float* attF  = out + 4194304;                                // [4194304, 12222464)
    unsigned short* feat_bf = (unsigned short*)(out + 13000000); // 3211264 fl -> ends 16211264
    unsigned short* wa_bf   = (unsigned short*)(out + 16300000); // 524288 fl  -> ends 16824288
    unsigned short* wihF_bf = (unsigned short*)(out + 17000000); // 2097152 fl -> ends 19097152
    float*          emb_seq = out + 20000000;                    // 1048576 fl -> ends 21048576

    // ---- prologue ----
    k_mean<<<512, 256, 0, stream>>>(features, mean_f);

    gemm64<<<dim3(1, 8), 256, 0, stream>>>(mean_f, F_DIM, init_h_W, F_DIM, H_,
                                           nullptr, 0, init_h_b, nullptr, nullptr,
                                           (float*)h_bf, H_, H_, F_DIM, 0, 1);
    gemm64<<<dim3(1, 8), 256, 0, stream>>>(mean_f, F_DIM, init_c_W, F_DIM, H_,
                                           nullptr, 0, init_c_b, nullptr, nullptr,
                                           c_st, H_, H_, F_DIM, 0, 0);

    // g_emb = emb @ W_ih[:, :E]^T + b_ih + b_hh   (f32, once)
    k_embgather<<<4096, 256, 0, stream>>>(embed, captions, emb_seq);
    gemm64<<<dim3(32, 32), 256, 0, stream>>>(emb_seq, E_, W_ih, E_ + F_DIM, 4 * H_,
                                             nullptr, 0, b_ih, nullptr, b_hh,
                                             g_emb, 4 * H_, 4 * H_, E_, 0, 0);

    // attF = features @ [W_a | W_ihF]^T : [3136, 2560]
    k_cast<<<dim3(2, 3136), 256, 0, stream>>>(features, feat_bf, 2048, 2048);
    k_cast<<<dim3(2, 512),  256, 0, stream>>>(W_a_W, wa_bf, 2048, 2048);
    k_cast<<<dim3(2, 2048), 256, 0, stream>>>(W_ih + E_, wihF_bf, 2048, E_ + F_DIM);
    gemm_mfma<<<dim3(25, 20), 256, 0, stream>>>(feat_bf, F_DIM, wa_bf, F_DIM, 512,
                                                wihF_bf, F_DIM, W_a_b,
                                                attF, 2560, 3136, 2560, F_DIM, 0);

    k_cast<<<dim3(1, 15000), 256, 0, stream>>>(fc_W, fcW_bf, 512, 512);

    // ---- recurrence: ONE persistent kernel, 32 steps, monotone grid barrier ----
    hipMemsetAsync(bar, 0, 128, stream);
    k_recur<<<NBLK_RECUR, 256, 0, stream>>>(h_bf, att2g, U_a_W, W_hh, U_a_b,
                                            attF, g_emb, v_a_W, v_a_b,
                                            c_st, h_hist, bar);

    // ---- logits: [T*B,H] @ fc_W^T + fc_b, permuted store to [B,T,V] ----
    gemm_mfma<<<dim3(16, 118), 256, 0, stream>>>(h_hist, H_, fcW_bf, H_, V_,
                                                 nullptr, 0, fc_b,
                                                 out, V_, 2048, V_, H_, 32);
}

// Round 5
// 1369.186 us; speedup vs baseline: 3.0067x; 3.0067x over previous
//
#include <hip/hip_runtime.h>
#include <math.h>

// decoderRNN: attention LSTM caption decoder, teacher-forced.
// B=64 L=49 F=2048 T=32 V=15000 E=H=A=512
#define B_ 64
#define L_ 49
#define F_DIM 2048
#define T_ 32
#define V_ 15000
#define E_ 512
#define H_ 512
#define A_ 512

typedef __attribute__((ext_vector_type(8))) short s16x8;
typedef __attribute__((ext_vector_type(4))) short s16x4;
typedef __attribute__((ext_vector_type(4))) float f32x4;

__device__ __forceinline__ unsigned short f2b(float x) {
    union { float f; unsigned int u; } v; v.f = x;
    unsigned int r = v.u + 0x7FFF + ((v.u >> 16) & 1);
    return (unsigned short)(r >> 16);
}
__device__ __forceinline__ float b2f(unsigned short u) {
    union { unsigned int i; float f; } v; v.i = ((unsigned int)u) << 16; return v.f;
}
__device__ __forceinline__ float tanhf_fast(float x) {
    x = fminf(fmaxf(x, -15.f), 15.f);
    const float e = __expf(2.f * x);
    return (e - 1.f) / (e + 1.f);
}

// ---- agent-scope coherent access (sc1: bypass non-coherent per-XCD L2) ----
__device__ __forceinline__ float aload_f(const float* p) {
    return __hip_atomic_load((const float*)p, __ATOMIC_RELAXED, __HIP_MEMORY_SCOPE_AGENT);
}
__device__ __forceinline__ void astore_f(float* p, float v) {
    __hip_atomic_store(p, v, __ATOMIC_RELAXED, __HIP_MEMORY_SCOPE_AGENT);
}
__device__ __forceinline__ unsigned long long aload_u64(const void* p) {
    return __hip_atomic_load((const unsigned long long*)p, __ATOMIC_RELAXED, __HIP_MEMORY_SCOPE_AGENT);
}
__device__ __forceinline__ void astore_u32(void* p, unsigned v) {
    __hip_atomic_store((unsigned*)p, v, __ATOMIC_RELAXED, __HIP_MEMORY_SCOPE_AGENT);
}

// ---------------- f32 -> bf16 cast, row-strided ----------------
__global__ __launch_bounds__(256)
void k_cast(const float* __restrict__ src, unsigned short* __restrict__ dst,
            int cols, int src_stride)
{
    const int r  = blockIdx.y;
    const int c4 = blockIdx.x * 256 + threadIdx.x;
    if (c4 * 4 >= cols) return;
    float4 v = *reinterpret_cast<const float4*>(src + (size_t)r * src_stride + c4 * 4);
    ushort4 o;
    o.x = f2b(v.x); o.y = f2b(v.y); o.z = f2b(v.z); o.w = f2b(v.w);
    *reinterpret_cast<ushort4*>(dst + (size_t)r * cols + c4 * 4) = o;
}

// ---- combined cast for [W_a(512 rows, ld 2048) ; W_ihF(2048 rows, ld 2560 off 512)] ----
__global__ __launch_bounds__(256)
void k_castW(const float* __restrict__ W_a, const float* __restrict__ W_ih,
             unsigned short* __restrict__ dst)
{
    const int r  = blockIdx.y;
    const int c4 = blockIdx.x * 256 + threadIdx.x;
    if (c4 * 4 >= 2048) return;
    const float* src = (r < 512) ? (W_a + (size_t)r * 2048)
                                 : (W_ih + (size_t)(r - 512) * 2560 + 512);
    float4 v = *reinterpret_cast<const float4*>(src + c4 * 4);
    ushort4 o;
    o.x = f2b(v.x); o.y = f2b(v.y); o.z = f2b(v.z); o.w = f2b(v.w);
    *reinterpret_cast<ushort4*>(dst + (size_t)r * 2048 + c4 * 4) = o;
}

// ---- bf16 MFMA GEMM: C[M,N] = A[M,K] @ W^T (+bias0 for n<N0) ----
// W rows [0,N0) from W0, [N0,N) from W1. 128x128 tile, BK=32, 4 waves.
// permT!=0: row = (m&63)*permT + (m>>6). obf!=0: store bf16.
#define LDSW 40
__global__ __launch_bounds__(256)
void gemm_mfma(const unsigned short* __restrict__ A, int lda,
               const unsigned short* __restrict__ W0, int ldw0, int N0,
               const unsigned short* __restrict__ W1, int ldw1,
               const float* __restrict__ bias0,
               float* __restrict__ C, int ldc,
               int M, int N, int K, int permT, int obf)
{
    __shared__ unsigned short As[128 * LDSW];
    __shared__ unsigned short Ws[128 * LDSW];

    const int tid  = threadIdx.x;
    const int m0   = blockIdx.x * 128;
    const int n0   = blockIdx.y * 128;
    const int wave = tid >> 6;
    const int lane = tid & 63;
    const int wr   = (wave >> 1) * 64;
    const int wc   = (wave & 1) * 64;

    f32x4 acc[4][4];
    #pragma unroll
    for (int i = 0; i < 4; ++i)
        #pragma unroll
        for (int j = 0; j < 4; ++j)
            acc[i][j] = (f32x4)(0.f);

    const int fr = lane & 15;
    const int fk = (lane >> 4) * 8;

    for (int kc = 0; kc < K; kc += 32) {
        float4 av[2], wv[2];
        #pragma unroll
        for (int i = 0; i < 2; ++i) {
            const int idx = tid + i * 256;
            const int row = idx >> 2;
            const int seg = idx & 3;
            av[i] = make_float4(0.f, 0.f, 0.f, 0.f);
            wv[i] = make_float4(0.f, 0.f, 0.f, 0.f);
            if (m0 + row < M)
                av[i] = *reinterpret_cast<const float4*>(A + (size_t)(m0 + row) * lda + kc + seg * 8);
            const int n_abs = n0 + row;
            if (n_abs < N) {
                const unsigned short* wrow = (n_abs < N0)
                    ? (W0 + (size_t)n_abs * ldw0)
                    : (W1 + (size_t)(n_abs - N0) * ldw1);
                wv[i] = *reinterpret_cast<const float4*>(wrow + kc + seg * 8);
            }
        }
        __syncthreads();
        #pragma unroll
        for (int i = 0; i < 2; ++i) {
            const int idx = tid + i * 256;
            const int row = idx >> 2;
            const int seg = idx & 3;
            *reinterpret_cast<float4*>(&As[row * LDSW + seg * 8]) = av[i];
            *reinterpret_cast<float4*>(&Ws[row * LDSW + seg * 8]) = wv[i];
        }
        __syncthreads();

        s16x8 afr[4], bfr[4];
        #pragma unroll
        for (int mf = 0; mf < 4; ++mf)
            afr[mf] = *reinterpret_cast<const s16x8*>(&As[(wr + mf * 16 + fr) * LDSW + fk]);
        #pragma unroll
        for (int nf = 0; nf < 4; ++nf)
            bfr[nf] = *reinterpret_cast<const s16x8*>(&Ws[(wc + nf * 16 + fr) * LDSW + fk]);

        #pragma unroll
        for (int mf = 0; mf < 4; ++mf)
            #pragma unroll
            for (int nf = 0; nf < 4; ++nf)
                acc[mf][nf] = __builtin_amdgcn_mfma_f32_16x16x32_bf16(
                    afr[mf], bfr[nf], acc[mf][nf], 0, 0, 0);
    }

    const int cr = (lane >> 4) * 4;
    const int cc = lane & 15;
    #pragma unroll
    for (int nf = 0; nf < 4; ++nf) {
        const int n = n0 + wc + nf * 16 + cc;
        if (n >= N) continue;
        const float bv = (bias0 && n < N0) ? bias0[n] : 0.f;
        #pragma unroll
        for (int mf = 0; mf < 4; ++mf) {
            #pragma unroll
            for (int r = 0; r < 4; ++r) {
                const int m = m0 + wr + mf * 16 + cr + r;
                if (m >= M) continue;
                const size_t row = permT ? ((size_t)(m & 63) * permT + (size_t)(m >> 6))
                                         : (size_t)m;
                const float v = acc[mf][nf][r] + bv;
                if (obf) ((unsigned short*)C)[row * (size_t)ldc + n] = f2b(v);
                else     C[row * (size_t)ldc + n] = v;
            }
        }
    }
}

// ---------------- generic tiled f32 GEMM (small prologue matmuls) ----------------
__global__ __launch_bounds__(256)
void gemm64(const float* __restrict__ A, int lda,
            const float* __restrict__ W0, int ldw0, int N0,
            const float* __restrict__ W1, int ldw1,
            const float* __restrict__ bias0, const float* __restrict__ bias1,
            const float* __restrict__ biasX,
            float* __restrict__ C, int ldc,
            int N, int K, int permT, int obf)
{
    __shared__ float As[16][64];
    __shared__ float Ws[16][64];

    const int tid = threadIdx.x;
    const int m0  = blockIdx.x * 64;
    const int n0  = blockIdx.y * 64;

    const int lr = tid >> 2;
    const int kq = tid & 3;

    const int n_abs = n0 + lr;
    const bool wvalid = (n_abs < N);
    const float* wrow = nullptr;
    if (wvalid)
        wrow = (n_abs < N0) ? (W0 + (size_t)n_abs * ldw0)
                            : (W1 + (size_t)(n_abs - N0) * ldw1);
    const float* arow = A + (size_t)(m0 + lr) * lda;

    const int ty = tid >> 4;
    const int tx = tid & 15;

    float acc[4][4] = {{0.f}};

    for (int kc = 0; kc < K; kc += 16) {
        float4 av = *reinterpret_cast<const float4*>(arow + kc + kq * 4);
        float4 wv = make_float4(0.f, 0.f, 0.f, 0.f);
        if (wvalid)
            wv = *reinterpret_cast<const float4*>(wrow + kc + kq * 4);

        __syncthreads();
        As[kq * 4 + 0][lr] = av.x;
        As[kq * 4 + 1][lr] = av.y;
        As[kq * 4 + 2][lr] = av.z;
        As[kq * 4 + 3][lr] = av.w;
        Ws[kq * 4 + 0][lr] = wv.x;
        Ws[kq * 4 + 1][lr] = wv.y;
        Ws[kq * 4 + 2][lr] = wv.z;
        Ws[kq * 4 + 3][lr] = wv.w;
        __syncthreads();

        #pragma unroll
        for (int kk = 0; kk < 16; ++kk) {
            const float4 a4 = *reinterpret_cast<const float4*>(&As[kk][ty * 4]);
            const float4 w4 = *reinterpret_cast<const float4*>(&Ws[kk][tx * 4]);
            const float aa[4] = {a4.x, a4.y, a4.z, a4.w};
            const float ww[4] = {w4.x, w4.y, w4.z, w4.w};
            #pragma unroll
            for (int i = 0; i < 4; ++i)
                #pragma unroll
                for (int j = 0; j < 4; ++j)
                    acc[i][j] = fmaf(aa[i], ww[j], acc[i][j]);
        }
    }

    #pragma unroll
    for (int i = 0; i < 4; ++i) {
        const int m = m0 + ty * 4 + i;
        #pragma unroll
        for (int j = 0; j < 4; ++j) {
            const int n = n0 + tx * 4 + j;
            if (n >= N) continue;
            float v = acc[i][j];
            if (bias0 && n < N0) v += bias0[n];
            if (bias1 && n >= N0) v += bias1[n - N0];
            if (biasX) v += biasX[n];
            const size_t row = permT ? ((size_t)(m & 63) * permT + (size_t)(m >> 6))
                                     : (size_t)m;
            if (obf) ((unsigned short*)C)[row * (size_t)ldc + n] = f2b(v);
            else     C[row * (size_t)ldc + n] = v;
        }
    }
}

// ---------------- mean over L ----------------
__global__ __launch_bounds__(256)
void k_mean(const float* __restrict__ feat, float* __restrict__ mean_f)
{
    const int idx = blockIdx.x * 256 + threadIdx.x;
    const int b = idx >> 11;
    const int f = idx & 2047;
    const float* p = feat + (size_t)b * L_ * F_DIM + f;
    float s = 0.f;
    #pragma unroll 7
    for (int l = 0; l < L_; ++l) s += p[(size_t)l * F_DIM];
    mean_f[idx] = s * (1.0f / 49.0f);
}

// ---------------- embedding gather ----------------
__global__ __launch_bounds__(256)
void k_embgather(const float* __restrict__ table, const int* __restrict__ caps,
                 float* __restrict__ emb_seq)
{
    const int idx = blockIdx.x * 256 + threadIdx.x;
    const int e   = idx & 511;
    const int row = idx >> 9;
    const int t   = row >> 6;
    const int b   = row & 63;
    const int tok = caps[b * T_ + t];
    emb_seq[idx] = table[(size_t)tok * E_ + e];
}

// ---------------- persistent recurrence kernel v2 ----------------
// 160 blocks x 256 thr, all co-resident (LDS ~27KB). Per step:
//  phase A (all blocks): block g computes att2g[:, g*16..+16] = h @ Wc^T via
//    MFMA; h read with agent-coherent loads, att2g written coherent.
//  phase B (blocks 0..127 = (b,half)): scores -> softmax -> gates -> LSTM.
// Cross-block data (h, att2g) ONLY via agent-scope atomics -> no L2-flush
// fences needed; read-only attF/g_emb/weights stay L2-resident all 32 steps.
// Barrier: monotone counter; arrive = fetch_add(RELEASE), poll = relaxed LOAD.
#define NBLK_RECUR 160u

__device__ __forceinline__ void gridbar(unsigned* cnt, unsigned target)
{
    __syncthreads();
    if (threadIdx.x == 0) {
        __hip_atomic_fetch_add(cnt, 1u, __ATOMIC_RELEASE, __HIP_MEMORY_SCOPE_AGENT);
        while (__hip_atomic_load(cnt, __ATOMIC_RELAXED, __HIP_MEMORY_SCOPE_AGENT) < target)
            __builtin_amdgcn_s_sleep(8);
    }
    __syncthreads();
}

__global__ __launch_bounds__(256)
void k_recur(unsigned short* __restrict__ hbf,      // [64][512] bf16 (coherent)
             float* __restrict__ att2g,             // [64][2560] (coherent)
             const float* __restrict__ U_a,         // [512][512]
             const float* __restrict__ W_hh,        // [2048][512]
             const float* __restrict__ U_a_b,       // [512]
             const unsigned short* __restrict__ attFb, // [3136][2560] bf16
             const float* __restrict__ g_emb,       // [32][64][2048]
             const float* __restrict__ v_w, const float* __restrict__ v_b,
             const float* __restrict__ c0,          // [64][512] initial c
             unsigned short* __restrict__ h_hist,   // [32][64][512] bf16
             unsigned* __restrict__ bar)
{
    __shared__ unsigned short Wc[16 * 520];
    __shared__ float a2[512];
    __shared__ float wl[64];
    __shared__ float gates[1024];
    __shared__ float hs[256];
    __shared__ float vws[512];

    const int g    = blockIdx.x;
    const int tid  = threadIdx.x;
    const int R    = g * 16;
    const int wave = tid >> 6;
    const int lane = tid & 63;

    // one-time: weight slice f32 -> bf16 LDS; v_w
    for (int idx = tid; idx < 2048; idx += 256) {
        const int r  = idx >> 7;
        const int kq = idx & 127;
        const int n  = R + r;
        const float* src = (n < 512) ? (U_a + (size_t)n * 512)
                                     : (W_hh + (size_t)(n - 512) * 512);
        float4 v = *reinterpret_cast<const float4*>(src + kq * 4);
        unsigned short* d = &Wc[r * 520 + kq * 4];
        d[0] = f2b(v.x); d[1] = f2b(v.y); d[2] = f2b(v.z); d[3] = f2b(v.w);
    }
    for (int i = tid; i < 512; i += 256) vws[i] = v_w[i];

    const int isB  = (g < 128);
    const int b    = g >> 1;
    const int half = g & 1;
    const float vb0 = v_b[0];

    // phase-B per-thread constants + register-resident cell state
    const int grp = tid >> 6;            // gate group i/f/g/o
    const int j4  = (tid & 63) * 4;
    const int gc  = grp * 512 + half * 256 + j4;   // gate col [0,2048)
    const int nn  = half * 256 + tid % 256;        // this thread's LSTM dim (tid<256)
    float creg = 0.f;
    if (isB) creg = c0[b * 512 + half * 256 + tid];
    __syncthreads();

    for (int t = 0; t < T_; ++t) {
        // ================= phase A: att2g = h @ [U_a|W_hh]^T =================
        {
            f32x4 acc = (f32x4)(0.f);
            const int frow = lane & 15;
            const unsigned char* hrow = (const unsigned char*)hbf
                + (size_t)(wave * 16 + frow) * 1024 + (lane >> 4) * 16;
            #pragma unroll
            for (int ks = 0; ks < 16; ++ks) {
                union { unsigned long long u[2]; s16x8 s; } A;
                A.u[0] = aload_u64(hrow + ks * 64);
                A.u[1] = aload_u64(hrow + ks * 64 + 8);
                s16x8 bf = *reinterpret_cast<const s16x8*>(&Wc[frow * 520 + ks * 32 + (lane >> 4) * 8]);
                acc = __builtin_amdgcn_mfma_f32_16x16x32_bf16(A.s, bf, acc, 0, 0, 0);
            }
            #pragma unroll
            for (int r = 0; r < 4; ++r) {
                const int babs = wave * 16 + (lane >> 4) * 4 + r;
                astore_f(&att2g[(size_t)babs * 2560 + R + frow], acc[r]);
            }
        }
        gridbar(bar, (unsigned)(2 * t + 1) * NBLK_RECUR);

        // ================= phase B =================
        if (isB) {
            // a2 = att2[b,:] + U_a_b (coherent read -> LDS)
            {
                union { unsigned long long u; float f[2]; } w2;
                w2.u = aload_u64(&att2g[(size_t)b * 2560 + 2 * tid]);
                a2[2 * tid]     = w2.f[0] + U_a_b[2 * tid];
                a2[2 * tid + 1] = w2.f[1] + U_a_b[2 * tid + 1];
            }
            __syncthreads();

            // scores over L=49 (att1 read bf16, L2-hot)
            for (int l = wave; l < L_; l += 4) {
                const s16x8 a1v = *reinterpret_cast<const s16x8*>(
                    attFb + (size_t)(b * L_ + l) * 2560 + lane * 8);
                float s = 0.f;
                #pragma unroll
                for (int j = 0; j < 8; ++j)
                    s += tanhf_fast(b2f((unsigned short)a1v[j]) + a2[lane * 8 + j]) * vws[lane * 8 + j];
                #pragma unroll
                for (int off = 32; off > 0; off >>= 1) s += __shfl_down(s, off);
                if (lane == 0) wl[l] = s + vb0;
            }
            __syncthreads();

            if (tid < 64) {
                float v = (lane < L_) ? wl[lane] : -3.0e38f;
                float mx = v;
                #pragma unroll
                for (int off = 32; off > 0; off >>= 1) mx = fmaxf(mx, __shfl_xor(mx, off));
                float e = (lane < L_) ? __expf(v - mx) : 0.f;
                float sum = e;
                #pragma unroll
                for (int off = 32; off > 0; off >>= 1) sum += __shfl_xor(sum, off);
                if (lane < L_) wl[lane] = e / sum;
            }
            __syncthreads();

            // gates: init (g_emb + h@W_hh via coherent att2g) + weighted featW
            {
                union { unsigned long long u; float f[2]; } q0, q1;
                q0.u = aload_u64(&att2g[(size_t)b * 2560 + 512 + gc]);
                q1.u = aload_u64(&att2g[(size_t)b * 2560 + 512 + gc + 2]);
                const float4 ge = *reinterpret_cast<const float4*>(
                    g_emb + ((size_t)t * 64 + b) * 2048 + gc);
                float s0 = ge.x + q0.f[0];
                float s1 = ge.y + q0.f[1];
                float s2 = ge.z + q1.f[0];
                float s3 = ge.w + q1.f[1];
                const unsigned short* fp = attFb + (size_t)(b * L_) * 2560 + 512 + gc;
                #pragma unroll 7
                for (int l = 0; l < L_; ++l) {
                    const float w = wl[l];
                    const s16x4 v = *reinterpret_cast<const s16x4*>(fp + (size_t)l * 2560);
                    s0 = fmaf(w, b2f((unsigned short)v[0]), s0);
                    s1 = fmaf(w, b2f((unsigned short)v[1]), s1);
                    s2 = fmaf(w, b2f((unsigned short)v[2]), s2);
                    s3 = fmaf(w, b2f((unsigned short)v[3]), s3);
                }
                float4* gq = reinterpret_cast<float4*>(&gates[grp * 256 + j4]);
                *gq = make_float4(s0, s1, s2, s3);
            }
            __syncthreads();

            // pointwise LSTM (c in registers)
            {
                const float gi = gates[tid], gf = gates[256 + tid];
                const float gg = gates[512 + tid], go = gates[768 + tid];
                const float i = 1.f / (1.f + __expf(-gi));
                const float f = 1.f / (1.f + __expf(-gf));
                const float gv = tanhf_fast(gg);
                const float o = 1.f / (1.f + __expf(-go));
                creg = f * creg + i * gv;
                hs[tid] = o * tanhf_fast(creg);
            }
            __syncthreads();

            // pack h -> bf16: coherent store to hbf, plain store to h_hist
            if (tid < 128) {
                const unsigned lo = f2b(hs[2 * tid]);
                const unsigned hi = f2b(hs[2 * tid + 1]);
                const unsigned pk = lo | (hi << 16);
                const int w32 = b * 256 + half * 128 + tid;
                astore_u32((unsigned*)hbf + w32, pk);
                ((unsigned*)h_hist)[(size_t)(t * 64 + b) * 256 + half * 128 + tid] = pk;
            }
        }
        gridbar(bar, (unsigned)(2 * t + 2) * NBLK_RECUR);
    }
}

extern "C" void kernel_launch(void* const* d_in, const int* in_sizes, int n_in,
                              void* d_out, int out_size, void* d_ws, size_t ws_size,
                              hipStream_t stream)
{
    const float* features = (const float*)d_in[0];
    const int*   captions = (const int*)d_in[1];
    const float* init_h_W = (const float*)d_in[3];
    const float* init_h_b = (const float*)d_in[4];
    const float* init_c_W = (const float*)d_in[5];
    const float* init_c_b = (const float*)d_in[6];
    const float* W_a_W    = (const float*)d_in[7];
    const float* W_a_b    = (const float*)d_in[8];
    const float* U_a_W    = (const float*)d_in[9];
    const float* U_a_b    = (const float*)d_in[10];
    const float* v_a_W    = (const float*)d_in[11];
    const float* v_a_b    = (const float*)d_in[12];
    const float* embed    = (const float*)d_in[13];
    const float* W_ih     = (const float*)d_in[14];
    const float* W_hh     = (const float*)d_in[15];
    const float* b_ih     = (const float*)d_in[16];
    const float* b_hh     = (const float*)d_in[17];
    const float* fc_W     = (const float*)d_in[18];
    const float* fc_b     = (const float*)d_in[19];
    float* out = (float*)d_out;

    // ---- workspace (floats), all disjoint, 8B-aligned bases ----
    float* ws      = (float*)d_ws;
    float* mean_f  = ws;                                        // [0, 131072)
    float* c_st    = ws + 131072;                               // [131072, 163840)
    unsigned short* h_bf   = (unsigned short*)(ws + 163840);    // 16384 fl
    unsigned short* h_hist = (unsigned short*)(ws + 180224);    // 524288 fl
    float* att2g   = ws + 704512;                               // 163840 fl
    unsigned short* fcW_bf = (unsigned short*)(ws + 868352);    // 3840000 fl
    unsigned* bar  = (unsigned*)(ws + 4708352);                 // 32 fl
    // high-water: 4,708,384 floats = 18.8 MB

    // ---- big transients in d_out (30,720,000 fl), disjoint, dead before logits ----
    float* g_emb = out;                                              // [0, 4194304)
    unsigned short* attF_bf = (unsigned short*)(out + 4194304);      // 4014080 fl -> ends 8208384
    unsigned short* feat_bf = (unsigned short*)(out + 13000000);     // 3211264 fl -> ends 16211264
    unsigned short* wcomb_bf = (unsigned short*)(out + 17000000);    // 2621440 fl -> ends 19621440
    float*          emb_seq  = out + 20000000;                       // 1048576 fl -> ends 21048576

    // ---- prologue ----
    k_mean<<<512, 256, 0, stream>>>(features, mean_f);

    gemm64<<<dim3(1, 8), 256, 0, stream>>>(mean_f, F_DIM, init_h_W, F_DIM, H_,
                                           nullptr, 0, init_h_b, nullptr, nullptr,
                                           (float*)h_bf, H_, H_, F_DIM, 0, 1);
    gemm64<<<dim3(1, 8), 256, 0, stream>>>(mean_f, F_DIM, init_c_W, F_DIM, H_,
                                           nullptr, 0, init_c_b, nullptr, nullptr,
                                           c_st, H_, H_, F_DIM, 0, 0);

    // g_emb = emb @ W_ih[:, :E]^T + b_ih + b_hh
    k_embgather<<<4096, 256, 0, stream>>>(embed, captions, emb_seq);
    gemm64<<<dim3(32, 32), 256, 0, stream>>>(emb_seq, E_, W_ih, E_ + F_DIM, 4 * H_,
                                             nullptr, 0, b_ih, nullptr, b_hh,
                                             g_emb, 4 * H_, 4 * H_, E_, 0, 0);

    // attF(bf16) = features @ [W_a | W_ihF]^T : [3136, 2560]
    k_cast<<<dim3(2, 3136), 256, 0, stream>>>(features, feat_bf, 2048, 2048);
    k_castW<<<dim3(2, 2560), 256, 0, stream>>>(W_a_W, W_ih, wcomb_bf);
    gemm_mfma<<<dim3(25, 20), 256, 0, stream>>>(feat_bf, F_DIM,
                                                wcomb_bf, 2048, 512,
                                                wcomb_bf + (size_t)512 * 2048, 2048,
                                                W_a_b,
                                                (float*)attF_bf, 2560,
                                                3136, 2560, F_DIM, 0, 1);

    k_cast<<<dim3(1, 15000), 256, 0, stream>>>(fc_W, fcW_bf, 512, 512);

    // ---- recurrence: ONE persistent kernel ----
    hipMemsetAsync(bar, 0, 128, stream);
    k_recur<<<NBLK_RECUR, 256, 0, stream>>>(h_bf, att2g, U_a_W, W_hh, U_a_b,
                                            attF_bf, g_emb, v_a_W, v_a_b,
                                            c_st, h_hist, bar);

    // ---- logits: [T*B,H] @ fc_W^T + fc_b, permuted store to [B,T,V] ----
    gemm_mfma<<<dim3(16, 118), 256, 0, stream>>>(h_hist, H_, fcW_bf, H_, V_,
                                                 nullptr, 0, fc_b,
                                                 out, V_, 2048, V_, H_, 32, 0);
}

// Round 6
// 1145.525 us; speedup vs baseline: 3.5937x; 1.1952x over previous
//
#include <hip/hip_runtime.h>
#include <math.h>

// decoderRNN: attention LSTM caption decoder, teacher-forced.
// B=64 L=49 F=2048 T=32 V=15000 E=H=A=512
#define B_ 64
#define L_ 49
#define F_DIM 2048
#define T_ 32
#define V_ 15000
#define E_ 512
#define H_ 512
#define A_ 512

typedef __attribute__((ext_vector_type(8))) short s16x8;
typedef __attribute__((ext_vector_type(4))) short s16x4;
typedef __attribute__((ext_vector_type(4))) float f32x4;

__device__ __forceinline__ unsigned short f2b(float x) {
    union { float f; unsigned int u; } v; v.f = x;
    unsigned int r = v.u + 0x7FFF + ((v.u >> 16) & 1);
    return (unsigned short)(r >> 16);
}
__device__ __forceinline__ float b2f(unsigned short u) {
    union { unsigned int i; float f; } v; v.i = ((unsigned int)u) << 16; return v.f;
}
__device__ __forceinline__ float rcp_fast(float x) {
    return __builtin_amdgcn_rcpf(x);
}
__device__ __forceinline__ float tanhf_fast(float x) {
    x = fminf(fmaxf(x, -15.f), 15.f);
    const float e = __expf(2.f * x);
    return (e - 1.f) * rcp_fast(e + 1.f);
}
__device__ __forceinline__ float sigmoid_fast(float x) {
    return rcp_fast(1.f + __expf(-x));
}

// ---- agent-scope coherent access (sc1: bypass non-coherent per-XCD L2) ----
__device__ __forceinline__ float aload_f(const float* p) {
    return __hip_atomic_load((const float*)p, __ATOMIC_RELAXED, __HIP_MEMORY_SCOPE_AGENT);
}
__device__ __forceinline__ void astore_f(float* p, float v) {
    __hip_atomic_store(p, v, __ATOMIC_RELAXED, __HIP_MEMORY_SCOPE_AGENT);
}
__device__ __forceinline__ unsigned long long aload_u64(const void* p) {
    return __hip_atomic_load((const unsigned long long*)p, __ATOMIC_RELAXED, __HIP_MEMORY_SCOPE_AGENT);
}
__device__ __forceinline__ void astore_u32(void* p, unsigned v) {
    __hip_atomic_store((unsigned*)p, v, __ATOMIC_RELAXED, __HIP_MEMORY_SCOPE_AGENT);
}

// ---------------- f32 -> bf16 cast, row-strided ----------------
__global__ __launch_bounds__(256)
void k_cast(const float* __restrict__ src, unsigned short* __restrict__ dst,
            int cols, int src_stride)
{
    const int r  = blockIdx.y;
    const int c4 = blockIdx.x * 256 + threadIdx.x;
    if (c4 * 4 >= cols) return;
    float4 v = *reinterpret_cast<const float4*>(src + (size_t)r * src_stride + c4 * 4);
    ushort4 o;
    o.x = f2b(v.x); o.y = f2b(v.y); o.z = f2b(v.z); o.w = f2b(v.w);
    *reinterpret_cast<ushort4*>(dst + (size_t)r * cols + c4 * 4) = o;
}

// ---- combined cast for [W_a(512 rows, ld 2048) ; W_ihF(2048 rows, ld 2560 off 512)] ----
__global__ __launch_bounds__(256)
void k_castW(const float* __restrict__ W_a, const float* __restrict__ W_ih,
             unsigned short* __restrict__ dst)
{
    const int r  = blockIdx.y;
    const int c4 = blockIdx.x * 256 + threadIdx.x;
    if (c4 * 4 >= 2048) return;
    const float* src = (r < 512) ? (W_a + (size_t)r * 2048)
                                 : (W_ih + (size_t)(r - 512) * 2560 + 512);
    float4 v = *reinterpret_cast<const float4*>(src + c4 * 4);
    ushort4 o;
    o.x = f2b(v.x); o.y = f2b(v.y); o.z = f2b(v.z); o.w = f2b(v.w);
    *reinterpret_cast<ushort4*>(dst + (size_t)r * 2048 + c4 * 4) = o;
}

// ---- bf16 MFMA GEMM: C[M,N] = A[M,K] @ W^T (+bias0 for n<N0) ----
#define LDSW 40
__global__ __launch_bounds__(256)
void gemm_mfma(const unsigned short* __restrict__ A, int lda,
               const unsigned short* __restrict__ W0, int ldw0, int N0,
               const unsigned short* __restrict__ W1, int ldw1,
               const float* __restrict__ bias0,
               float* __restrict__ C, int ldc,
               int M, int N, int K, int permT, int obf)
{
    __shared__ unsigned short As[128 * LDSW];
    __shared__ unsigned short Ws[128 * LDSW];

    const int tid  = threadIdx.x;
    const int m0   = blockIdx.x * 128;
    const int n0   = blockIdx.y * 128;
    const int wave = tid >> 6;
    const int lane = tid & 63;
    const int wr   = (wave >> 1) * 64;
    const int wc   = (wave & 1) * 64;

    f32x4 acc[4][4];
    #pragma unroll
    for (int i = 0; i < 4; ++i)
        #pragma unroll
        for (int j = 0; j < 4; ++j)
            acc[i][j] = (f32x4)(0.f);

    const int fr = lane & 15;
    const int fk = (lane >> 4) * 8;

    for (int kc = 0; kc < K; kc += 32) {
        float4 av[2], wv[2];
        #pragma unroll
        for (int i = 0; i < 2; ++i) {
            const int idx = tid + i * 256;
            const int row = idx >> 2;
            const int seg = idx & 3;
            av[i] = make_float4(0.f, 0.f, 0.f, 0.f);
            wv[i] = make_float4(0.f, 0.f, 0.f, 0.f);
            if (m0 + row < M)
                av[i] = *reinterpret_cast<const float4*>(A + (size_t)(m0 + row) * lda + kc + seg * 8);
            const int n_abs = n0 + row;
            if (n_abs < N) {
                const unsigned short* wrow = (n_abs < N0)
                    ? (W0 + (size_t)n_abs * ldw0)
                    : (W1 + (size_t)(n_abs - N0) * ldw1);
                wv[i] = *reinterpret_cast<const float4*>(wrow + kc + seg * 8);
            }
        }
        __syncthreads();
        #pragma unroll
        for (int i = 0; i < 2; ++i) {
            const int idx = tid + i * 256;
            const int row = idx >> 2;
            const int seg = idx & 3;
            *reinterpret_cast<float4*>(&As[row * LDSW + seg * 8]) = av[i];
            *reinterpret_cast<float4*>(&Ws[row * LDSW + seg * 8]) = wv[i];
        }
        __syncthreads();

        s16x8 afr[4], bfr[4];
        #pragma unroll
        for (int mf = 0; mf < 4; ++mf)
            afr[mf] = *reinterpret_cast<const s16x8*>(&As[(wr + mf * 16 + fr) * LDSW + fk]);
        #pragma unroll
        for (int nf = 0; nf < 4; ++nf)
            bfr[nf] = *reinterpret_cast<const s16x8*>(&Ws[(wc + nf * 16 + fr) * LDSW + fk]);

        #pragma unroll
        for (int mf = 0; mf < 4; ++mf)
            #pragma unroll
            for (int nf = 0; nf < 4; ++nf)
                acc[mf][nf] = __builtin_amdgcn_mfma_f32_16x16x32_bf16(
                    afr[mf], bfr[nf], acc[mf][nf], 0, 0, 0);
    }

    const int cr = (lane >> 4) * 4;
    const int cc = lane & 15;
    #pragma unroll
    for (int nf = 0; nf < 4; ++nf) {
        const int n = n0 + wc + nf * 16 + cc;
        if (n >= N) continue;
        const float bv = (bias0 && n < N0) ? bias0[n] : 0.f;
        #pragma unroll
        for (int mf = 0; mf < 4; ++mf) {
            #pragma unroll
            for (int r = 0; r < 4; ++r) {
                const int m = m0 + wr + mf * 16 + cr + r;
                if (m >= M) continue;
                const size_t row = permT ? ((size_t)(m & 63) * permT + (size_t)(m >> 6))
                                         : (size_t)m;
                const float v = acc[mf][nf][r] + bv;
                if (obf) ((unsigned short*)C)[row * (size_t)ldc + n] = f2b(v);
                else     C[row * (size_t)ldc + n] = v;
            }
        }
    }
}

// ---------------- generic tiled f32 GEMM (small prologue matmuls) ----------------
__global__ __launch_bounds__(256)
void gemm64(const float* __restrict__ A, int lda,
            const float* __restrict__ W0, int ldw0, int N0,
            const float* __restrict__ W1, int ldw1,
            const float* __restrict__ bias0, const float* __restrict__ bias1,
            const float* __restrict__ biasX,
            float* __restrict__ C, int ldc,
            int N, int K, int permT, int obf)
{
    __shared__ float As[16][64];
    __shared__ float Ws[16][64];

    const int tid = threadIdx.x;
    const int m0  = blockIdx.x * 64;
    const int n0  = blockIdx.y * 64;

    const int lr = tid >> 2;
    const int kq = tid & 3;

    const int n_abs = n0 + lr;
    const bool wvalid = (n_abs < N);
    const float* wrow = nullptr;
    if (wvalid)
        wrow = (n_abs < N0) ? (W0 + (size_t)n_abs * ldw0)
                            : (W1 + (size_t)(n_abs - N0) * ldw1);
    const float* arow = A + (size_t)(m0 + lr) * lda;

    const int ty = tid >> 4;
    const int tx = tid & 15;

    float acc[4][4] = {{0.f}};

    for (int kc = 0; kc < K; kc += 16) {
        float4 av = *reinterpret_cast<const float4*>(arow + kc + kq * 4);
        float4 wv = make_float4(0.f, 0.f, 0.f, 0.f);
        if (wvalid)
            wv = *reinterpret_cast<const float4*>(wrow + kc + kq * 4);

        __syncthreads();
        As[kq * 4 + 0][lr] = av.x;
        As[kq * 4 + 1][lr] = av.y;
        As[kq * 4 + 2][lr] = av.z;
        As[kq * 4 + 3][lr] = av.w;
        Ws[kq * 4 + 0][lr] = wv.x;
        Ws[kq * 4 + 1][lr] = wv.y;
        Ws[kq * 4 + 2][lr] = wv.z;
        Ws[kq * 4 + 3][lr] = wv.w;
        __syncthreads();

        #pragma unroll
        for (int kk = 0; kk < 16; ++kk) {
            const float4 a4 = *reinterpret_cast<const float4*>(&As[kk][ty * 4]);
            const float4 w4 = *reinterpret_cast<const float4*>(&Ws[kk][tx * 4]);
            const float aa[4] = {a4.x, a4.y, a4.z, a4.w};
            const float ww[4] = {w4.x, w4.y, w4.z, w4.w};
            #pragma unroll
            for (int i = 0; i < 4; ++i)
                #pragma unroll
                for (int j = 0; j < 4; ++j)
                    acc[i][j] = fmaf(aa[i], ww[j], acc[i][j]);
        }
    }

    #pragma unroll
    for (int i = 0; i < 4; ++i) {
        const int m = m0 + ty * 4 + i;
        #pragma unroll
        for (int j = 0; j < 4; ++j) {
            const int n = n0 + tx * 4 + j;
            if (n >= N) continue;
            float v = acc[i][j];
            if (bias0 && n < N0) v += bias0[n];
            if (bias1 && n >= N0) v += bias1[n - N0];
            if (biasX) v += biasX[n];
            const size_t row = permT ? ((size_t)(m & 63) * permT + (size_t)(m >> 6))
                                     : (size_t)m;
            if (obf) ((unsigned short*)C)[row * (size_t)ldc + n] = f2b(v);
            else     C[row * (size_t)ldc + n] = v;
        }
    }
}

// ---------------- mean over L ----------------
__global__ __launch_bounds__(256)
void k_mean(const float* __restrict__ feat, float* __restrict__ mean_f)
{
    const int idx = blockIdx.x * 256 + threadIdx.x;
    const int b = idx >> 11;
    const int f = idx & 2047;
    const float* p = feat + (size_t)b * L_ * F_DIM + f;
    float s = 0.f;
    #pragma unroll 7
    for (int l = 0; l < L_; ++l) s += p[(size_t)l * F_DIM];
    mean_f[idx] = s * (1.0f / 49.0f);
}

// ---------------- embedding gather ----------------
__global__ __launch_bounds__(256)
void k_embgather(const float* __restrict__ table, const int* __restrict__ caps,
                 float* __restrict__ emb_seq)
{
    const int idx = blockIdx.x * 256 + threadIdx.x;
    const int e   = idx & 511;
    const int row = idx >> 9;
    const int t   = row >> 6;
    const int b   = row & 63;
    const int tok = caps[b * T_ + t];
    emb_seq[idx] = table[(size_t)tok * E_ + e];
}

// ---------------- persistent recurrence kernel v3 ----------------
// 80 blocks x 512 thr (8 waves -> 2 waves/SIMD). Per step:
//  phase A (all 80): block g owns cols R=g*32..+31 of [U_a;W_hh] (bf16 LDS);
//    8 waves: wave w -> col-tile (w>>2), h-rows (w&3)*16; MFMA 16x16x32.
//  phase B (blocks 0..63, one per batch): scores -> softmax -> gates -> LSTM.
// Cross-block data (h, att2g) ONLY via agent-scope relaxed atomics (L2-bypass,
// never dirty in L2). Barrier: explicit s_waitcnt vmcnt(0) by EVERY wave, then
// RELAXED fetch_add + relaxed poll -> no buffer_wbl2 / buffer_inv anywhere.
#define NBLK_RECUR 80u

__device__ __forceinline__ void gridbar(unsigned* cnt, unsigned target)
{
    asm volatile("s_waitcnt vmcnt(0)" ::: "memory");   // my stores -> coherence point
    __syncthreads();
    if (threadIdx.x == 0) {
        __hip_atomic_fetch_add(cnt, 1u, __ATOMIC_RELAXED, __HIP_MEMORY_SCOPE_AGENT);
        while (__hip_atomic_load(cnt, __ATOMIC_RELAXED, __HIP_MEMORY_SCOPE_AGENT) < target)
            __builtin_amdgcn_s_sleep(2);
    }
    __syncthreads();
}

__global__ __launch_bounds__(512)
void k_recur(unsigned short* __restrict__ hbf,      // [64][512] bf16 (coherent)
             float* __restrict__ att2g,             // [64][2560] (coherent)
             const float* __restrict__ U_a,         // [512][512]
             const float* __restrict__ W_hh,        // [2048][512]
             const float* __restrict__ U_a_b,       // [512]
             const unsigned short* __restrict__ attFb, // [3136][2560] bf16
             const float* __restrict__ g_emb,       // [32][64][2048]
             const float* __restrict__ v_w, const float* __restrict__ v_b,
             const float* __restrict__ c0,          // [64][512] initial c
             unsigned short* __restrict__ h_hist,   // [32][64][512] bf16
             unsigned* __restrict__ bar)
{
    __shared__ unsigned short Wc[32 * 520];   // this block's 32 weight rows
    __shared__ float a2[512];
    __shared__ float wl[64];
    __shared__ float gates[2048];
    __shared__ float hs[512];
    __shared__ float vws[512];

    const int g    = blockIdx.x;
    const int tid  = threadIdx.x;
    const int R    = g * 32;
    const int wave = tid >> 6;
    const int lane = tid & 63;

    // one-time: 32 weight rows f32 -> bf16 LDS; v_w
    for (int idx = tid; idx < 4096; idx += 512) {   // 32 rows x 128 float4
        const int r  = idx >> 7;
        const int kq = idx & 127;
        const int n  = R + r;
        const float* src = (n < 512) ? (U_a + (size_t)n * 512)
                                     : (W_hh + (size_t)(n - 512) * 512);
        float4 v = *reinterpret_cast<const float4*>(src + kq * 4);
        unsigned short* d = &Wc[r * 520 + kq * 4];
        d[0] = f2b(v.x); d[1] = f2b(v.y); d[2] = f2b(v.z); d[3] = f2b(v.w);
    }
    if (tid < 512) vws[tid] = v_w[tid];

    const int isB = (g < 64);
    const int b   = g;
    const float vb0 = v_b[0];

    // phase-B constants + register cell state (thread owns LSTM dim n=tid)
    const int grp = tid >> 7;           // gate group i/f/g/o
    const int jj  = (tid & 127) * 4;    // col within gate
    const int gc  = grp * 512 + jj;
    float creg = 0.f;
    if (isB) creg = c0[b * 512 + tid];

    // phase-A constants
    const int tcol  = wave >> 2;        // 0/1: which 16-col tile
    const int rows0 = (wave & 3) * 16;  // h-row base
    const int frow  = lane & 15;
    const int fko   = (lane >> 4) * 8;  // k sub-offset (shorts)
    __syncthreads();

    for (int t = 0; t < T_; ++t) {
        // ===== phase A: att2g[:, R+tcol*16 ..+16] = h @ Wc^T =====
        {
            f32x4 acc = (f32x4)(0.f);
            const unsigned char* hrow = (const unsigned char*)hbf
                + (size_t)(rows0 + frow) * 1024 + (lane >> 4) * 16;
            #pragma unroll
            for (int ks = 0; ks < 16; ++ks) {
                union { unsigned long long u[2]; s16x8 s; } A;
                A.u[0] = aload_u64(hrow + ks * 64);
                A.u[1] = aload_u64(hrow + ks * 64 + 8);
                s16x8 bf = *reinterpret_cast<const s16x8*>(
                    &Wc[(tcol * 16 + frow) * 520 + ks * 32 + fko]);
                acc = __builtin_amdgcn_mfma_f32_16x16x32_bf16(A.s, bf, acc, 0, 0, 0);
            }
            const int col = R + tcol * 16 + frow;
            #pragma unroll
            for (int r = 0; r < 4; ++r) {
                const int babs = rows0 + (lane >> 4) * 4 + r;
                astore_f(&att2g[(size_t)babs * 2560 + col], acc[r]);
            }
        }
        gridbar(bar, (unsigned)(2 * t + 1) * NBLK_RECUR);

        // ===== phase B =====
        if (isB) {
            a2[tid] = aload_f(&att2g[(size_t)b * 2560 + tid]) + U_a_b[tid];
            __syncthreads();

            // scores over L=49 (8 waves)
            for (int l = wave; l < L_; l += 8) {
                const s16x8 a1v = *reinterpret_cast<const s16x8*>(
                    attFb + (size_t)(b * L_ + l) * 2560 + lane * 8);
                float s = 0.f;
                #pragma unroll
                for (int j = 0; j < 8; ++j)
                    s += tanhf_fast(b2f((unsigned short)a1v[j]) + a2[lane * 8 + j]) * vws[lane * 8 + j];
                #pragma unroll
                for (int off = 32; off > 0; off >>= 1) s += __shfl_down(s, off);
                if (lane == 0) wl[l] = s + vb0;
            }
            __syncthreads();

            if (tid < 64) {
                float v = (tid < L_) ? wl[tid] : -3.0e38f;
                float mx = v;
                #pragma unroll
                for (int off = 32; off > 0; off >>= 1) mx = fmaxf(mx, __shfl_xor(mx, off));
                float e = (tid < L_) ? __expf(v - mx) : 0.f;
                float sum = e;
                #pragma unroll
                for (int off = 32; off > 0; off >>= 1) sum += __shfl_xor(sum, off);
                if (tid < L_) wl[tid] = e * rcp_fast(sum);
            }
            __syncthreads();

            // gates: (g_emb + h@W_hh) + softmax-weighted featW
            {
                union { unsigned long long u; float f[2]; } q0, q1;
                q0.u = aload_u64(&att2g[(size_t)b * 2560 + 512 + gc]);
                q1.u = aload_u64(&att2g[(size_t)b * 2560 + 512 + gc + 2]);
                const float4 ge = *reinterpret_cast<const float4*>(
                    g_emb + ((size_t)t * 64 + b) * 2048 + gc);
                float s0 = ge.x + q0.f[0];
                float s1 = ge.y + q0.f[1];
                float s2 = ge.z + q1.f[0];
                float s3 = ge.w + q1.f[1];
                const unsigned short* fp = attFb + (size_t)(b * L_) * 2560 + 512 + gc;
                #pragma unroll 7
                for (int l = 0; l < L_; ++l) {
                    const float w = wl[l];
                    const s16x4 v = *reinterpret_cast<const s16x4*>(fp + (size_t)l * 2560);
                    s0 = fmaf(w, b2f((unsigned short)v[0]), s0);
                    s1 = fmaf(w, b2f((unsigned short)v[1]), s1);
                    s2 = fmaf(w, b2f((unsigned short)v[2]), s2);
                    s3 = fmaf(w, b2f((unsigned short)v[3]), s3);
                }
                *reinterpret_cast<float4*>(&gates[gc]) = make_float4(s0, s1, s2, s3);
            }
            __syncthreads();

            // pointwise LSTM (c in registers; thread owns dim n=tid)
            {
                const float gi = gates[tid],        gf = gates[512 + tid];
                const float gg = gates[1024 + tid], go = gates[1536 + tid];
                const float i = sigmoid_fast(gi);
                const float f = sigmoid_fast(gf);
                const float gv = tanhf_fast(gg);
                const float o = sigmoid_fast(go);
                creg = f * creg + i * gv;
                hs[tid] = o * tanhf_fast(creg);
            }
            __syncthreads();

            // pack h -> bf16: coherent store to hbf, plain store to h_hist
            if (tid < 256) {
                const unsigned lo = f2b(hs[2 * tid]);
                const unsigned hi = f2b(hs[2 * tid + 1]);
                const unsigned pk = lo | (hi << 16);
                astore_u32((unsigned*)hbf + b * 256 + tid, pk);
                ((unsigned*)h_hist)[(size_t)(t * 64 + b) * 256 + tid] = pk;
            }
        }
        gridbar(bar, (unsigned)(2 * t + 2) * NBLK_RECUR);
    }
}

extern "C" void kernel_launch(void* const* d_in, const int* in_sizes, int n_in,
                              void* d_out, int out_size, void* d_ws, size_t ws_size,
                              hipStream_t stream)
{
    const float* features = (const float*)d_in[0];
    const int*   captions = (const int*)d_in[1];
    const float* init_h_W = (const float*)d_in[3];
    const float* init_h_b = (const float*)d_in[4];
    const float* init_c_W = (const float*)d_in[5];
    const float* init_c_b = (const float*)d_in[6];
    const float* W_a_W    = (const float*)d_in[7];
    const float* W_a_b    = (const float*)d_in[8];
    const float* U_a_W    = (const float*)d_in[9];
    const float* U_a_b    = (const float*)d_in[10];
    const float* v_a_W    = (const float*)d_in[11];
    const float* v_a_b    = (const float*)d_in[12];
    const float* embed    = (const float*)d_in[13];
    const float* W_ih     = (const float*)d_in[14];
    const float* W_hh     = (const float*)d_in[15];
    const float* b_ih     = (const float*)d_in[16];
    const float* b_hh     = (const float*)d_in[17];
    const float* fc_W     = (const float*)d_in[18];
    const float* fc_b     = (const float*)d_in[19];
    float* out = (float*)d_out;

    // ---- workspace (floats), all disjoint ----
    float* ws      = (float*)d_ws;
    float* mean_f  = ws;                                        // [0, 131072)
    float* c_st    = ws + 131072;                               // [131072, 163840)
    unsigned short* h_bf   = (unsigned short*)(ws + 163840);    // 16384 fl
    unsigned short* h_hist = (unsigned short*)(ws + 180224);    // 524288 fl
    float* att2g   = ws + 704512;                               // 163840 fl
    unsigned short* fcW_bf = (unsigned short*)(ws + 868352);    // 3840000 fl
    unsigned* bar  = (unsigned*)(ws + 4708352);                 // 32 fl

    // ---- big transients in d_out (30,720,000 fl), disjoint, dead before logits ----
    float* g_emb = out;                                              // [0, 4194304)
    unsigned short* attF_bf = (unsigned short*)(out + 4194304);      // -> ends 8208384
    unsigned short* feat_bf = (unsigned short*)(out + 13000000);     // -> ends 16211264
    unsigned short* wcomb_bf = (unsigned short*)(out + 17000000);    // -> ends 19621440
    float*          emb_seq  = out + 20000000;                       // -> ends 21048576

    // ---- prologue ----
    k_mean<<<512, 256, 0, stream>>>(features, mean_f);

    gemm64<<<dim3(1, 8), 256, 0, stream>>>(mean_f, F_DIM, init_h_W, F_DIM, H_,
                                           nullptr, 0, init_h_b, nullptr, nullptr,
                                           (float*)h_bf, H_, H_, F_DIM, 0, 1);
    gemm64<<<dim3(1, 8), 256, 0, stream>>>(mean_f, F_DIM, init_c_W, F_DIM, H_,
                                           nullptr, 0, init_c_b, nullptr, nullptr,
                                           c_st, H_, H_, F_DIM, 0, 0);

    // g_emb = emb @ W_ih[:, :E]^T + b_ih + b_hh
    k_embgather<<<4096, 256, 0, stream>>>(embed, captions, emb_seq);
    gemm64<<<dim3(32, 32), 256, 0, stream>>>(emb_seq, E_, W_ih, E_ + F_DIM, 4 * H_,
                                             nullptr, 0, b_ih, nullptr, b_hh,
                                             g_emb, 4 * H_, 4 * H_, E_, 0, 0);

    // attF(bf16) = features @ [W_a | W_ihF]^T : [3136, 2560]
    k_cast<<<dim3(2, 3136), 256, 0, stream>>>(features, feat_bf, 2048, 2048);
    k_castW<<<dim3(2, 2560), 256, 0, stream>>>(W_a_W, W_ih, wcomb_bf);
    gemm_mfma<<<dim3(25, 20), 256, 0, stream>>>(feat_bf, F_DIM,
                                                wcomb_bf, 2048, 512,
                                                wcomb_bf + (size_t)512 * 2048, 2048,
                                                W_a_b,
                                                (float*)attF_bf, 2560,
                                                3136, 2560, F_DIM, 0, 1);

    k_cast<<<dim3(1, 15000), 256, 0, stream>>>(fc_W, fcW_bf, 512, 512);

    // ---- recurrence: ONE persistent kernel ----
    hipMemsetAsync(bar, 0, 128, stream);
    k_recur<<<NBLK_RECUR, 512, 0, stream>>>(h_bf, att2g, U_a_W, W_hh, U_a_b,
                                            attF_bf, g_emb, v_a_W, v_a_b,
                                            c_st, h_hist, bar);

    // ---- logits: [T*B,H] @ fc_W^T + fc_b, permuted store to [B,T,V] ----
    gemm_mfma<<<dim3(16, 118), 256, 0, stream>>>(h_hist, H_, fcW_bf, H_, V_,
                                                 nullptr, 0, fc_b,
                                                 out, V_, 2048, V_, H_, 32, 0);
}

// Round 7
// 1056.143 us; speedup vs baseline: 3.8979x; 1.0846x over previous
//
#include <hip/hip_runtime.h>
#include <math.h>

// decoderRNN: attention LSTM caption decoder, teacher-forced.
// B=64 L=49 F=2048 T=32 V=15000 E=H=A=512
#define B_ 64
#define L_ 49
#define F_DIM 2048
#define T_ 32
#define V_ 15000
#define E_ 512
#define H_ 512
#define A_ 512

typedef __attribute__((ext_vector_type(8))) short s16x8;
typedef __attribute__((ext_vector_type(4))) short s16x4;
typedef __attribute__((ext_vector_type(4))) float f32x4;

__device__ __forceinline__ unsigned short f2b(float x) {
    union { float f; unsigned int u; } v; v.f = x;
    unsigned int r = v.u + 0x7FFF + ((v.u >> 16) & 1);
    return (unsigned short)(r >> 16);
}
__device__ __forceinline__ float b2f(unsigned short u) {
    union { unsigned int i; float f; } v; v.i = ((unsigned int)u) << 16; return v.f;
}
__device__ __forceinline__ float rcp_fast(float x) {
    return __builtin_amdgcn_rcpf(x);
}
__device__ __forceinline__ float tanhf_fast(float x) {
    x = fminf(fmaxf(x, -15.f), 15.f);
    const float e = __expf(2.f * x);
    return (e - 1.f) * rcp_fast(e + 1.f);
}
__device__ __forceinline__ float sigmoid_fast(float x) {
    return rcp_fast(1.f + __expf(-x));
}

// ---- agent-scope coherent access (LLC, bypass non-coherent per-XCD L2) ----
__device__ __forceinline__ float aload_f(const float* p) {
    return __hip_atomic_load((const float*)p, __ATOMIC_RELAXED, __HIP_MEMORY_SCOPE_AGENT);
}
__device__ __forceinline__ void astore_f(float* p, float v) {
    __hip_atomic_store(p, v, __ATOMIC_RELAXED, __HIP_MEMORY_SCOPE_AGENT);
}
__device__ __forceinline__ unsigned long long aload_u64(const void* p) {
    return __hip_atomic_load((const unsigned long long*)p, __ATOMIC_RELAXED, __HIP_MEMORY_SCOPE_AGENT);
}
__device__ __forceinline__ void astore_u32(void* p, unsigned v) {
    __hip_atomic_store((unsigned*)p, v, __ATOMIC_RELAXED, __HIP_MEMORY_SCOPE_AGENT);
}
__device__ __forceinline__ unsigned apoll(const unsigned* p) {
    return __hip_atomic_load(p, __ATOMIC_RELAXED, __HIP_MEMORY_SCOPE_AGENT);
}
__device__ __forceinline__ void abump(unsigned* p) {
    __hip_atomic_fetch_add(p, 1u, __ATOMIC_RELAXED, __HIP_MEMORY_SCOPE_AGENT);
}
__device__ __forceinline__ void aset(unsigned* p, unsigned v) {
    __hip_atomic_store(p, v, __ATOMIC_RELAXED, __HIP_MEMORY_SCOPE_AGENT);
}

// ---------------- f32 -> bf16 cast, row-strided ----------------
__global__ __launch_bounds__(256)
void k_cast(const float* __restrict__ src, unsigned short* __restrict__ dst,
            int cols, int src_stride)
{
    const int r  = blockIdx.y;
    const int c4 = blockIdx.x * 256 + threadIdx.x;
    if (c4 * 4 >= cols) return;
    float4 v = *reinterpret_cast<const float4*>(src + (size_t)r * src_stride + c4 * 4);
    ushort4 o;
    o.x = f2b(v.x); o.y = f2b(v.y); o.z = f2b(v.z); o.w = f2b(v.w);
    *reinterpret_cast<ushort4*>(dst + (size_t)r * cols + c4 * 4) = o;
}

// ---- combined cast for [W_a(512 rows, ld 2048) ; W_ihF(2048 rows, ld 2560 off 512)] ----
__global__ __launch_bounds__(256)
void k_castW(const float* __restrict__ W_a, const float* __restrict__ W_ih,
             unsigned short* __restrict__ dst)
{
    const int r  = blockIdx.y;
    const int c4 = blockIdx.x * 256 + threadIdx.x;
    if (c4 * 4 >= 2048) return;
    const float* src = (r < 512) ? (W_a + (size_t)r * 2048)
                                 : (W_ih + (size_t)(r - 512) * 2560 + 512);
    float4 v = *reinterpret_cast<const float4*>(src + c4 * 4);
    ushort4 o;
    o.x = f2b(v.x); o.y = f2b(v.y); o.z = f2b(v.z); o.w = f2b(v.w);
    *reinterpret_cast<ushort4*>(dst + (size_t)r * 2048 + c4 * 4) = o;
}

// ---- bias sum: o = a + b ----
__global__ __launch_bounds__(256)
void k_addbias(const float* __restrict__ a, const float* __restrict__ b,
               float* __restrict__ o, int n)
{
    const int i = blockIdx.x * 256 + threadIdx.x;
    if (i < n) o[i] = a[i] + b[i];
}

// ---- bf16 MFMA GEMM: C[M,N] = A[M,K] @ W^T (+bias0 for n<N0) ----
#define LDSW 40
__global__ __launch_bounds__(256)
void gemm_mfma(const unsigned short* __restrict__ A, int lda,
               const unsigned short* __restrict__ W0, int ldw0, int N0,
               const unsigned short* __restrict__ W1, int ldw1,
               const float* __restrict__ bias0,
               float* __restrict__ C, int ldc,
               int M, int N, int K, int permT, int obf)
{
    __shared__ unsigned short As[128 * LDSW];
    __shared__ unsigned short Ws[128 * LDSW];

    const int tid  = threadIdx.x;
    const int m0   = blockIdx.x * 128;
    const int n0   = blockIdx.y * 128;
    const int wave = tid >> 6;
    const int lane = tid & 63;
    const int wr   = (wave >> 1) * 64;
    const int wc   = (wave & 1) * 64;

    f32x4 acc[4][4];
    #pragma unroll
    for (int i = 0; i < 4; ++i)
        #pragma unroll
        for (int j = 0; j < 4; ++j)
            acc[i][j] = (f32x4)(0.f);

    const int fr = lane & 15;
    const int fk = (lane >> 4) * 8;

    for (int kc = 0; kc < K; kc += 32) {
        float4 av[2], wv[2];
        #pragma unroll
        for (int i = 0; i < 2; ++i) {
            const int idx = tid + i * 256;
            const int row = idx >> 2;
            const int seg = idx & 3;
            av[i] = make_float4(0.f, 0.f, 0.f, 0.f);
            wv[i] = make_float4(0.f, 0.f, 0.f, 0.f);
            if (m0 + row < M)
                av[i] = *reinterpret_cast<const float4*>(A + (size_t)(m0 + row) * lda + kc + seg * 8);
            const int n_abs = n0 + row;
            if (n_abs < N) {
                const unsigned short* wrow = (n_abs < N0)
                    ? (W0 + (size_t)n_abs * ldw0)
                    : (W1 + (size_t)(n_abs - N0) * ldw1);
                wv[i] = *reinterpret_cast<const float4*>(wrow + kc + seg * 8);
            }
        }
        __syncthreads();
        #pragma unroll
        for (int i = 0; i < 2; ++i) {
            const int idx = tid + i * 256;
            const int row = idx >> 2;
            const int seg = idx & 3;
            *reinterpret_cast<float4*>(&As[row * LDSW + seg * 8]) = av[i];
            *reinterpret_cast<float4*>(&Ws[row * LDSW + seg * 8]) = wv[i];
        }
        __syncthreads();

        s16x8 afr[4], bfr[4];
        #pragma unroll
        for (int mf = 0; mf < 4; ++mf)
            afr[mf] = *reinterpret_cast<const s16x8*>(&As[(wr + mf * 16 + fr) * LDSW + fk]);
        #pragma unroll
        for (int nf = 0; nf < 4; ++nf)
            bfr[nf] = *reinterpret_cast<const s16x8*>(&Ws[(wc + nf * 16 + fr) * LDSW + fk]);

        #pragma unroll
        for (int mf = 0; mf < 4; ++mf)
            #pragma unroll
            for (int nf = 0; nf < 4; ++nf)
                acc[mf][nf] = __builtin_amdgcn_mfma_f32_16x16x32_bf16(
                    afr[mf], bfr[nf], acc[mf][nf], 0, 0, 0);
    }

    const int cr = (lane >> 4) * 4;
    const int cc = lane & 15;
    #pragma unroll
    for (int nf = 0; nf < 4; ++nf) {
        const int n = n0 + wc + nf * 16 + cc;
        if (n >= N) continue;
        const float bv = (bias0 && n < N0) ? bias0[n] : 0.f;
        #pragma unroll
        for (int mf = 0; mf < 4; ++mf) {
            #pragma unroll
            for (int r = 0; r < 4; ++r) {
                const int m = m0 + wr + mf * 16 + cr + r;
                if (m >= M) continue;
                const size_t row = permT ? ((size_t)(m & 63) * permT + (size_t)(m >> 6))
                                         : (size_t)m;
                const float v = acc[mf][nf][r] + bv;
                if (obf) ((unsigned short*)C)[row * (size_t)ldc + n] = f2b(v);
                else     C[row * (size_t)ldc + n] = v;
            }
        }
    }
}

// ---------------- generic tiled f32 GEMM (tiny prologue matmuls) ----------------
__global__ __launch_bounds__(256)
void gemm64(const float* __restrict__ A, int lda,
            const float* __restrict__ W0, int ldw0, int N0,
            const float* __restrict__ W1, int ldw1,
            const float* __restrict__ bias0, const float* __restrict__ bias1,
            const float* __restrict__ biasX,
            float* __restrict__ C, int ldc,
            int N, int K, int permT, int obf)
{
    __shared__ float As[16][64];
    __shared__ float Ws[16][64];

    const int tid = threadIdx.x;
    const int m0  = blockIdx.x * 64;
    const int n0  = blockIdx.y * 64;

    const int lr = tid >> 2;
    const int kq = tid & 3;

    const int n_abs = n0 + lr;
    const bool wvalid = (n_abs < N);
    const float* wrow = nullptr;
    if (wvalid)
        wrow = (n_abs < N0) ? (W0 + (size_t)n_abs * ldw0)
                            : (W1 + (size_t)(n_abs - N0) * ldw1);
    const float* arow = A + (size_t)(m0 + lr) * lda;

    const int ty = tid >> 4;
    const int tx = tid & 15;

    float acc[4][4] = {{0.f}};

    for (int kc = 0; kc < K; kc += 16) {
        float4 av = *reinterpret_cast<const float4*>(arow + kc + kq * 4);
        float4 wv = make_float4(0.f, 0.f, 0.f, 0.f);
        if (wvalid)
            wv = *reinterpret_cast<const float4*>(wrow + kc + kq * 4);

        __syncthreads();
        As[kq * 4 + 0][lr] = av.x;
        As[kq * 4 + 1][lr] = av.y;
        As[kq * 4 + 2][lr] = av.z;
        As[kq * 4 + 3][lr] = av.w;
        Ws[kq * 4 + 0][lr] = wv.x;
        Ws[kq * 4 + 1][lr] = wv.y;
        Ws[kq * 4 + 2][lr] = wv.z;
        Ws[kq * 4 + 3][lr] = wv.w;
        __syncthreads();

        #pragma unroll
        for (int kk = 0; kk < 16; ++kk) {
            const float4 a4 = *reinterpret_cast<const float4*>(&As[kk][ty * 4]);
            const float4 w4 = *reinterpret_cast<const float4*>(&Ws[kk][tx * 4]);
            const float aa[4] = {a4.x, a4.y, a4.z, a4.w};
            const float ww[4] = {w4.x, w4.y, w4.z, w4.w};
            #pragma unroll
            for (int i = 0; i < 4; ++i)
                #pragma unroll
                for (int j = 0; j < 4; ++j)
                    acc[i][j] = fmaf(aa[i], ww[j], acc[i][j]);
        }
    }

    #pragma unroll
    for (int i = 0; i < 4; ++i) {
        const int m = m0 + ty * 4 + i;
        #pragma unroll
        for (int j = 0; j < 4; ++j) {
            const int n = n0 + tx * 4 + j;
            if (n >= N) continue;
            float v = acc[i][j];
            if (bias0 && n < N0) v += bias0[n];
            if (bias1 && n >= N0) v += bias1[n - N0];
            if (biasX) v += biasX[n];
            const size_t row = permT ? ((size_t)(m & 63) * permT + (size_t)(m >> 6))
                                     : (size_t)m;
            if (obf) ((unsigned short*)C)[row * (size_t)ldc + n] = f2b(v);
            else     C[row * (size_t)ldc + n] = v;
        }
    }
}

// ---------------- mean over L ----------------
__global__ __launch_bounds__(256)
void k_mean(const float* __restrict__ feat, float* __restrict__ mean_f)
{
    const int idx = blockIdx.x * 256 + threadIdx.x;
    const int b = idx >> 11;
    const int f = idx & 2047;
    const float* p = feat + (size_t)b * L_ * F_DIM + f;
    float s = 0.f;
    #pragma unroll 7
    for (int l = 0; l < L_; ++l) s += p[(size_t)l * F_DIM];
    mean_f[idx] = s * (1.0f / 49.0f);
}

// ---------------- embedding gather (bf16 out) ----------------
__global__ __launch_bounds__(256)
void k_embgather(const float* __restrict__ table, const int* __restrict__ caps,
                 unsigned short* __restrict__ emb_bf)
{
    const int idx = blockIdx.x * 256 + threadIdx.x;
    const int e   = idx & 511;
    const int row = idx >> 9;
    const int t   = row >> 6;
    const int b   = row & 63;
    const int tok = caps[b * T_ + t];
    emb_bf[idx] = f2b(table[(size_t)tok * E_ + e]);
}

// ---------------- persistent recurrence kernel v4: event-pump sync ----------------
// 81 blocks x 512 thr: 80 workers + 1 root event pump (block 80).
// Events per step (counters at LLC, generation broadcast to 8 group lines):
//   genH   : all 64 B-blocks stored h          -> workers start phase A
//   genAtt : blocks 0..15 stored att-cols      -> B starts scores (overlaps rest of A)
//   genFull: all 80 blocks stored att2g        -> B does gates add
// Cross-block data (h, att2g) only via agent-scope relaxed atomics (never dirty
// in per-XCD L2 -> no flush/inv needed; vmcnt(0) before arrival publishes).
#define NBLK_RECUR 81u
// bar uint layout: [0]=cntB [16]=cntAatt [32]=cntAfull
//                  [64+grp*16]=genH [192+grp*16]=genAtt [320+grp*16]=genFull

__global__ __launch_bounds__(512)
void k_recur(unsigned short* __restrict__ hbf,      // [64][512] bf16 (coherent)
             float* __restrict__ att2g,             // [64][2560] (coherent)
             const float* __restrict__ U_a,         // [512][512]
             const float* __restrict__ W_hh,        // [2048][512]
             const float* __restrict__ U_a_b,       // [512]
             const unsigned short* __restrict__ attFb, // [3136][2560] bf16
             const float* __restrict__ g_emb,       // [32][64][2048]
             const float* __restrict__ v_w, const float* __restrict__ v_b,
             const float* __restrict__ c0,          // [64][512] initial c
             unsigned short* __restrict__ h_hist,   // [32][64][512] bf16
             unsigned* __restrict__ bar)
{
    const int g   = blockIdx.x;
    const int tid = threadIdx.x;

    // ---------- root event pump ----------
    if (g == 80) {
        if (tid == 0) {
            for (int t = 0; t < T_; ++t) {
                while (apoll(bar + 0) < (unsigned)(t * 64)) __builtin_amdgcn_s_sleep(1);
                #pragma unroll
                for (int i = 0; i < 8; ++i) aset(bar + 64 + i * 16, (unsigned)(t + 1));
                while (apoll(bar + 16) < (unsigned)((t + 1) * 16)) __builtin_amdgcn_s_sleep(1);
                #pragma unroll
                for (int i = 0; i < 8; ++i) aset(bar + 192 + i * 16, (unsigned)(t + 1));
                while (apoll(bar + 32) < (unsigned)((t + 1) * 80)) __builtin_amdgcn_s_sleep(1);
                #pragma unroll
                for (int i = 0; i < 8; ++i) aset(bar + 320 + i * 16, (unsigned)(t + 1));
            }
        }
        return;
    }

    // ---------- workers ----------
    __shared__ unsigned short Wc[32 * 520];   // this block's 32 weight rows (bf16)
    __shared__ float a2[512];
    __shared__ float wl[64];
    __shared__ float gates[2048];
    __shared__ float hs[512];
    __shared__ float vws[512];
    __shared__ float vub[512];

    const int R    = g * 32;
    const int wave = tid >> 6;
    const int lane = tid & 63;
    const int grp  = g & 7;

    // one-time: 32 weight rows f32 -> bf16 LDS; v_w; U_a_b
    for (int idx = tid; idx < 4096; idx += 512) {   // 32 rows x 128 float4
        const int r  = idx >> 7;
        const int kq = idx & 127;
        const int n  = R + r;
        const float* src = (n < 512) ? (U_a + (size_t)n * 512)
                                     : (W_hh + (size_t)(n - 512) * 512);
        float4 v = *reinterpret_cast<const float4*>(src + kq * 4);
        unsigned short* d = &Wc[r * 520 + kq * 4];
        d[0] = f2b(v.x); d[1] = f2b(v.y); d[2] = f2b(v.z); d[3] = f2b(v.w);
    }
    vws[tid] = v_w[tid];
    vub[tid] = U_a_b[tid];

    const int isB = (g < 64);
    const int b   = g;
    const float vb0 = v_b[0];

    // phase-B constants + register cell state (thread owns LSTM dim n=tid)
    const int ggrp = tid >> 7;          // gate group i/f/g/o
    const int jj   = (tid & 127) * 4;
    const int gc   = ggrp * 512 + jj;
    float creg = 0.f;
    if (isB) creg = c0[b * 512 + tid];

    // phase-A constants
    const int tcol  = wave >> 2;        // 0/1: which 16-col tile
    const int rows0 = (wave & 3) * 16;  // h-row base
    const int frow  = lane & 15;
    const int fko   = (lane >> 4) * 8;
    __syncthreads();

    for (int t = 0; t < T_; ++t) {
        // ===== wait: h(t) ready =====
        if (tid == 0)
            while (apoll(bar + 64 + grp * 16) < (unsigned)(t + 1)) __builtin_amdgcn_s_sleep(2);
        __syncthreads();

        // ===== phase A: att2g[:, R+tcol*16 ..+16] = h @ Wc^T =====
        {
            f32x4 acc = (f32x4)(0.f);
            const unsigned char* hrow = (const unsigned char*)hbf
                + (size_t)(rows0 + frow) * 1024 + (lane >> 4) * 16;
            #pragma unroll
            for (int ks = 0; ks < 16; ++ks) {
                union { unsigned long long u[2]; s16x8 s; } A;
                A.u[0] = aload_u64(hrow + ks * 64);
                A.u[1] = aload_u64(hrow + ks * 64 + 8);
                s16x8 bf = *reinterpret_cast<const s16x8*>(
                    &Wc[(tcol * 16 + frow) * 520 + ks * 32 + fko]);
                acc = __builtin_amdgcn_mfma_f32_16x16x32_bf16(A.s, bf, acc, 0, 0, 0);
            }
            const int col = R + tcol * 16 + frow;
            #pragma unroll
            for (int r = 0; r < 4; ++r) {
                const int babs = rows0 + (lane >> 4) * 4 + r;
                astore_f(&att2g[(size_t)babs * 2560 + col], acc[r]);
            }
        }
        asm volatile("s_waitcnt vmcnt(0)" ::: "memory");
        __syncthreads();
        if (tid == 0) {
            if (g < 16) abump(bar + 16);   // att cols done
            abump(bar + 32);               // full slice done
        }

        // ===== phase B (blocks 0..63) =====
        if (isB) {
            if (tid == 0)
                while (apoll(bar + 192 + grp * 16) < (unsigned)(t + 1)) __builtin_amdgcn_s_sleep(2);
            __syncthreads();

            a2[tid] = aload_f(&att2g[(size_t)b * 2560 + tid]) + vub[tid];
            __syncthreads();

            // scores over L=49 (8 waves)
            for (int l = wave; l < L_; l += 8) {
                const s16x8 a1v = *reinterpret_cast<const s16x8*>(
                    attFb + (size_t)(b * L_ + l) * 2560 + lane * 8);
                float s = 0.f;
                #pragma unroll
                for (int j = 0; j < 8; ++j)
                    s += tanhf_fast(b2f((unsigned short)a1v[j]) + a2[lane * 8 + j]) * vws[lane * 8 + j];
                #pragma unroll
                for (int off = 32; off > 0; off >>= 1) s += __shfl_down(s, off);
                if (lane == 0) wl[l] = s + vb0;
            }
            __syncthreads();

            if (tid < 64) {
                float v = (tid < L_) ? wl[tid] : -3.0e38f;
                float mx = v;
                #pragma unroll
                for (int off = 32; off > 0; off >>= 1) mx = fmaxf(mx, __shfl_xor(mx, off));
                float e = (tid < L_) ? __expf(v - mx) : 0.f;
                float sum = e;
                #pragma unroll
                for (int off = 32; off > 0; off >>= 1) sum += __shfl_xor(sum, off);
                if (tid < L_) wl[tid] = e * rcp_fast(sum);
            }

            // wait: full att2g (gate cols) ready — overlaps with scores above
            if (tid == 0)
                while (apoll(bar + 320 + grp * 16) < (unsigned)(t + 1)) __builtin_amdgcn_s_sleep(2);
            __syncthreads();

            // gates: (g_emb + h@W_hh) + softmax-weighted featW
            {
                union { unsigned long long u; float f[2]; } q0, q1;
                q0.u = aload_u64(&att2g[(size_t)b * 2560 + 512 + gc]);
                q1.u = aload_u64(&att2g[(size_t)b * 2560 + 512 + gc + 2]);
                const float4 ge = *reinterpret_cast<const float4*>(
                    g_emb + ((size_t)t * 64 + b) * 2048 + gc);
                float s0 = ge.x + q0.f[0];
                float s1 = ge.y + q0.f[1];
                float s2 = ge.z + q1.f[0];
                float s3 = ge.w + q1.f[1];
                const unsigned short* fp = attFb + (size_t)(b * L_) * 2560 + 512 + gc;
                #pragma unroll 7
                for (int l = 0; l < L_; ++l) {
                    const float w = wl[l];
                    const s16x4 v = *reinterpret_cast<const s16x4*>(fp + (size_t)l * 2560);
                    s0 = fmaf(w, b2f((unsigned short)v[0]), s0);
                    s1 = fmaf(w, b2f((unsigned short)v[1]), s1);
                    s2 = fmaf(w, b2f((unsigned short)v[2]), s2);
                    s3 = fmaf(w, b2f((unsigned short)v[3]), s3);
                }
                *reinterpret_cast<float4*>(&gates[gc]) = make_float4(s0, s1, s2, s3);
            }
            __syncthreads();

            // pointwise LSTM (c in registers; thread owns dim n=tid)
            {
                const float gi = gates[tid],        gf = gates[512 + tid];
                const float gg = gates[1024 + tid], go = gates[1536 + tid];
                const float i = sigmoid_fast(gi);
                const float f = sigmoid_fast(gf);
                const float gv = tanhf_fast(gg);
                const float o = sigmoid_fast(go);
                creg = f * creg + i * gv;
                hs[tid] = o * tanhf_fast(creg);
            }
            __syncthreads();

            // pack h -> bf16: coherent store to hbf, plain store to h_hist
            if (tid < 256) {
                const unsigned lo = f2b(hs[2 * tid]);
                const unsigned hi = f2b(hs[2 * tid + 1]);
                const unsigned pk = lo | (hi << 16);
                astore_u32((unsigned*)hbf + b * 256 + tid, pk);
                ((unsigned*)h_hist)[(size_t)(t * 64 + b) * 256 + tid] = pk;
            }
            asm volatile("s_waitcnt vmcnt(0)" ::: "memory");
            __syncthreads();
            if (tid == 0) abump(bar + 0);
        }
    }
}

extern "C" void kernel_launch(void* const* d_in, const int* in_sizes, int n_in,
                              void* d_out, int out_size, void* d_ws, size_t ws_size,
                              hipStream_t stream)
{
    const float* features = (const float*)d_in[0];
    const int*   captions = (const int*)d_in[1];
    const float* init_h_W = (const float*)d_in[3];
    const float* init_h_b = (const float*)d_in[4];
    const float* init_c_W = (const float*)d_in[5];
    const float* init_c_b = (const float*)d_in[6];
    const float* W_a_W    = (const float*)d_in[7];
    const float* W_a_b    = (const float*)d_in[8];
    const float* U_a_W    = (const float*)d_in[9];
    const float* U_a_b    = (const float*)d_in[10];
    const float* v_a_W    = (const float*)d_in[11];
    const float* v_a_b    = (const float*)d_in[12];
    const float* embed    = (const float*)d_in[13];
    const float* W_ih     = (const float*)d_in[14];
    const float* W_hh     = (const float*)d_in[15];
    const float* b_ih     = (const float*)d_in[16];
    const float* b_hh     = (const float*)d_in[17];
    const float* fc_W     = (const float*)d_in[18];
    const float* fc_b     = (const float*)d_in[19];
    float* out = (float*)d_out;

    // ---- workspace (floats), all disjoint ----
    float* ws      = (float*)d_ws;
    float* mean_f  = ws;                                        // [0, 131072)
    float* c_st    = ws + 131072;                               // [131072, 163840)
    unsigned short* h_bf   = (unsigned short*)(ws + 163840);    // 16384 fl
    unsigned short* h_hist = (unsigned short*)(ws + 180224);    // 524288 fl
    float* att2g   = ws + 704512;                               // 163840 fl
    unsigned short* fcW_bf = (unsigned short*)(ws + 868352);    // 3840000 fl
    unsigned* bar  = (unsigned*)(ws + 4708352);                 // 512 uints
    float* bsum    = ws + 4709000;                              // 2048 fl

    // ---- big transients in d_out (30,720,000 fl), disjoint, dead before logits ----
    float* g_emb = out;                                              // [0, 4194304)
    unsigned short* attF_bf  = (unsigned short*)(out + 4194304);     // -> ends 8208384
    unsigned short* feat_bf  = (unsigned short*)(out + 13000000);    // -> ends 16211264
    unsigned short* wcomb_bf = (unsigned short*)(out + 17000000);    // -> ends 19621440
    unsigned short* emb_bf   = (unsigned short*)(out + 20000000);    // -> ends 20524288
    unsigned short* wihE_bf  = (unsigned short*)(out + 21000000);    // -> ends 21524288

    // ---- prologue ----
    k_mean<<<512, 256, 0, stream>>>(features, mean_f);

    gemm64<<<dim3(1, 8), 256, 0, stream>>>(mean_f, F_DIM, init_h_W, F_DIM, H_,
                                           nullptr, 0, init_h_b, nullptr, nullptr,
                                           (float*)h_bf, H_, H_, F_DIM, 0, 1);
    gemm64<<<dim3(1, 8), 256, 0, stream>>>(mean_f, F_DIM, init_c_W, F_DIM, H_,
                                           nullptr, 0, init_c_b, nullptr, nullptr,
                                           c_st, H_, H_, F_DIM, 0, 0);

    // g_emb = emb @ W_ih[:, :E]^T + (b_ih + b_hh)   (bf16 MFMA)
    k_embgather<<<4096, 256, 0, stream>>>(embed, captions, emb_bf);
    k_cast<<<dim3(1, 2048), 256, 0, stream>>>(W_ih, wihE_bf, 512, E_ + F_DIM);
    k_addbias<<<8, 256, 0, stream>>>(b_ih, b_hh, bsum, 2048);
    gemm_mfma<<<dim3(16, 16), 256, 0, stream>>>(emb_bf, E_,
                                                wihE_bf, E_, 4 * H_,
                                                wihE_bf, E_, bsum,
                                                g_emb, 4 * H_,
                                                2048, 4 * H_, E_, 0, 0);

    // attF(bf16) = features @ [W_a | W_ihF]^T : [3136, 2560]
    k_cast<<<dim3(2, 3136), 256, 0, stream>>>(features, feat_bf, 2048, 2048);
    k_castW<<<dim3(2, 2560), 256, 0, stream>>>(W_a_W, W_ih, wcomb_bf);
    gemm_mfma<<<dim3(25, 20), 256, 0, stream>>>(feat_bf, F_DIM,
                                                wcomb_bf, 2048, 512,
                                                wcomb_bf + (size_t)512 * 2048, 2048,
                                                W_a_b,
                                                (float*)attF_bf, 2560,
                                                3136, 2560, F_DIM, 0, 1);

    k_cast<<<dim3(1, 15000), 256, 0, stream>>>(fc_W, fcW_bf, 512, 512);

    // ---- recurrence: ONE persistent kernel, event-pump sync ----
    hipMemsetAsync(bar, 0, 2048, stream);
    k_recur<<<NBLK_RECUR, 512, 0, stream>>>(h_bf, att2g, U_a_W, W_hh, U_a_b,
                                            attF_bf, g_emb, v_a_W, v_a_b,
                                            c_st, h_hist, bar);

    // ---- logits: [T*B,H] @ fc_W^T + fc_b, permuted store to [B,T,V] ----
    gemm_mfma<<<dim3(16, 118), 256, 0, stream>>>(h_hist, H_, fcW_bf, H_, V_,
                                                 nullptr, 0, fc_b,
                                                 out, V_, 2048, V_, H_, 32, 0);
}